// Round 4
// baseline (818.588 us; speedup 1.0000x reference)
//
#include <hip/hip_runtime.h>
#include <limits.h>

#pragma clang fp contract(off)

#define NB 512
#define NC 151
#define KDIM 4096
#define KS 8
#define KCH (KDIM/KS)      // 512
#define GRB 16             // gemm rows per block
#define PST 152            // padded row stride (floats), 16B aligned
#define NK 16              // commits per round
#define NMS_TH 0.3f

typedef unsigned long long ull;

// ---------------- DPP wave64 reductions ----------------
template <int CTRL>
__device__ __forceinline__ int dpp_i(int identity, int x) {
  return __builtin_amdgcn_update_dpp(identity, x, CTRL, 0xF, 0xF, false);
}
__device__ __forceinline__ float wave_max_bcast(float x) {
  const int ID = __float_as_int(-3.4e38f);
  x = fmaxf(x, __int_as_float(dpp_i<0x111>(ID, __float_as_int(x))));  // row_shr:1
  x = fmaxf(x, __int_as_float(dpp_i<0x112>(ID, __float_as_int(x))));  // row_shr:2
  x = fmaxf(x, __int_as_float(dpp_i<0x114>(ID, __float_as_int(x))));  // row_shr:4
  x = fmaxf(x, __int_as_float(dpp_i<0x118>(ID, __float_as_int(x))));  // row_shr:8
  x = fmaxf(x, __int_as_float(dpp_i<0x142>(ID, __float_as_int(x))));  // row_bcast:15
  x = fmaxf(x, __int_as_float(dpp_i<0x143>(ID, __float_as_int(x))));  // row_bcast:31
  return __int_as_float(__builtin_amdgcn_readlane(__float_as_int(x), 63));
}
__device__ __forceinline__ int wave_min_bcast_i(int x) {
  int y;
  y = dpp_i<0x111>(INT_MAX, x); x = (x < y) ? x : y;
  y = dpp_i<0x112>(INT_MAX, x); x = (x < y) ? x : y;
  y = dpp_i<0x114>(INT_MAX, x); x = (x < y) ? x : y;
  y = dpp_i<0x118>(INT_MAX, x); x = (x < y) ? x : y;
  y = dpp_i<0x142>(INT_MAX, x); x = (x < y) ? x : y;
  y = dpp_i<0x143>(INT_MAX, x); x = (x < y) ? x : y;
  return __builtin_amdgcn_readlane(x, 63);
}

// exact reference IoU arithmetic (fp contract off file-wide)
__device__ __forceinline__ bool overlap_ge(const float4& c, const float4& o) {
  float areaC = (c.z - c.x + 1.0f) * (c.w - c.y + 1.0f);
  float areaJ = (o.z - o.x + 1.0f) * (o.w - o.y + 1.0f);
  float iw = fminf(c.z, o.z) - fmaxf(c.x, o.x) + 1.0f;
  float ih = fminf(c.w, o.w) - fmaxf(c.y, o.y) + 1.0f;
  iw = fmaxf(iw, 0.0f); ih = fmaxf(ih, 0.0f);
  float inter = iw * ih;
  float uni = areaC + areaJ - inter;
  return inter / uni >= NMS_TH;
}

__device__ __forceinline__ bool mbit(const unsigned m[5], int c) {
  bool r = false;
#pragma unroll
  for (int k = 0; k < 5; ++k) r = (k == (c >> 5)) ? (((m[k] >> (c & 31)) & 1u) != 0) : r;
  return r;
}

// ---------------- GEMM split-K partials: A scalar-uniform, W coalesced, no LDS ----------------
__global__ __launch_bounds__(192) void gemm_partial(
    const float* __restrict__ A, const float* __restrict__ W, float* __restrict__ part)
{
  const int c = threadIdx.x;
  const int rb = blockIdx.x, ks = blockIdx.y;
  if (c >= NC) return;
  const float* Ab = A + (size_t)rb * GRB * KDIM + (size_t)ks * KCH;
  const float* wp = W + (size_t)ks * KCH * NC + c;
  float acc[GRB];
#pragma unroll
  for (int r = 0; r < GRB; ++r) acc[r] = 0.f;
  for (int k = 0; k < KCH; k += 4) {
    float w0 = wp[(size_t)(k + 0) * NC];
    float w1 = wp[(size_t)(k + 1) * NC];
    float w2 = wp[(size_t)(k + 2) * NC];
    float w3 = wp[(size_t)(k + 3) * NC];
#pragma unroll
    for (int r = 0; r < GRB; ++r) {
      const float* ar = Ab + (size_t)r * KDIM + k;   // block-uniform -> scalar loads
      acc[r] = fmaf(ar[0], w0, acc[r]);
      acc[r] = fmaf(ar[1], w1, acc[r]);
      acc[r] = fmaf(ar[2], w2, acc[r]);
      acc[r] = fmaf(ar[3], w3, acc[r]);
    }
  }
  float* o = part + ((size_t)ks * NB + (size_t)rb * GRB) * PST + c;
#pragma unroll
  for (int r = 0; r < GRB; ++r) o[(size_t)r * PST] = acc[r];
}

// coalesced obj_dists writer (runs after decode; out not on decode critical path)
__global__ void reduce_out(const float* __restrict__ part, const float* __restrict__ bias,
                           float* __restrict__ out) {
  int i = blockIdx.x * 256 + threadIdx.x;
  if (i >= NB * NC) return;
  int r = i / NC, c = i - r * NC;
  float acc = 0.f;
#pragma unroll
  for (int ks = 0; ks < KS; ++ks) acc += part[((size_t)ks * NB + r) * PST + c];
  out[i] = acc + bias[c];
}

// fallback (ws too small)
__global__ __launch_bounds__(192) void gemm_full(
    const float* __restrict__ A, const float* __restrict__ W,
    const float* __restrict__ bias, float* __restrict__ out)
{
  int c = threadIdx.x;
  int r0 = blockIdx.x * 4;
  if (c >= NC) return;
  const float* a = A + (size_t)r0 * KDIM;
  const float* wp = W + c;
  float a0 = 0.f, a1 = 0.f, a2 = 0.f, a3 = 0.f;
#pragma unroll 8
  for (int k = 0; k < KDIM; ++k) {
    float w = wp[(size_t)k * NC];
    a0 = fmaf(a[k],            w, a0);
    a1 = fmaf(a[k + KDIM],     w, a1);
    a2 = fmaf(a[k + 2 * KDIM], w, a2);
    a3 = fmaf(a[k + 3 * KDIM], w, a3);
  }
  float bb = bias[c];
  out[(size_t)(r0 + 0) * NC + c] = a0 + bb;
  out[(size_t)(r0 + 1) * NC + c] = a1 + bb;
  out[(size_t)(r0 + 2) * NC + c] = a2 + bb;
  out[(size_t)(r0 + 3) * NC + c] = a3 + bb;
}

// ---------------- Multi-commit greedy NMS decode (K=16) ----------------
// USEWS: src = partials [KS][NB][PST], probs stored to probsws [NB][PST] (fast rescan).
// else : src = obj_dists [NB][NC], rescan recomputes expf.
template <bool USEWS>
__global__ __launch_bounds__(512) void decode_kernel(
    const float* __restrict__ src, const float* __restrict__ bias,
    const float* __restrict__ boxes, float* __restrict__ probsws,
    float* __restrict__ commits)
{
  __shared__ ull cand[NB];     // 4 KB
  __shared__ int ovlm[NB];     // 2 KB
  __shared__ int winlds[NK];   // 64 B
  const int j = threadIdx.x;
  const int lane = j & 63;

  // ---- phase A: softmax constants + per-row top-16 (stable desc) ----
  float lv[NK]; int lc[NK];
#pragma unroll
  for (int t = 0; t < NK; ++t) { lv[t] = -3.4e38f; lc[t] = 0; }
  auto ins = [&](float v, int c) {
    if (v > lv[NK - 1]) {
      lv[NK - 1] = v; lc[NK - 1] = c;
#pragma unroll
      for (int q = NK - 1; q > 0; --q) {
        if (lv[q] > lv[q - 1]) {
          float tv = lv[q]; lv[q] = lv[q - 1]; lv[q - 1] = tv;
          int tc = lc[q]; lc[q] = lc[q - 1]; lc[q - 1] = tc;
        }
      }
    }
  };

  float m_ = -3.4e38f, s_ = 0.f;
  const float* xr = USEWS ? nullptr : (src + (size_t)j * NC);
  float* pr = USEWS ? (probsws + (size_t)j * PST) : nullptr;

  if (USEWS) {
    // pass1: sum split-K partials + bias -> logits into pr; track max
    for (int c4 = 0; c4 < PST / 4; ++c4) {
      float x0 = 0.f, x1 = 0.f, x2 = 0.f, x3 = 0.f;
#pragma unroll
      for (int ks = 0; ks < KS; ++ks) {
        const float4 v = *(const float4*)(src + ((size_t)ks * NB + j) * PST + c4 * 4);
        x0 += v.x; x1 += v.y; x2 += v.z; x3 += v.w;
      }
      int c = c4 * 4;
      x0 += bias[c];
      if (c + 1 < NC) x1 += bias[c + 1];
      if (c + 2 < NC) x2 += bias[c + 2];
      if (c + 3 < NC) x3 += bias[c + 3];
      float4 st; st.x = x0; st.y = x1; st.z = x2; st.w = x3;
      *(float4*)(pr + c4 * 4) = st;
      m_ = fmaxf(m_, x0);
      if (c + 1 < NC) m_ = fmaxf(m_, x1);
      if (c + 2 < NC) m_ = fmaxf(m_, x2);
      if (c + 3 < NC) m_ = fmaxf(m_, x3);
    }
    // pass2: exp values back into pr; accumulate s ascending
    for (int c4 = 0; c4 < PST / 4; ++c4) {
      float4 v = *(const float4*)(pr + c4 * 4);
      int c = c4 * 4;
      float e0 = expf(v.x - m_);
      float e1 = (c + 1 < NC) ? expf(v.y - m_) : 0.f;
      float e2 = (c + 2 < NC) ? expf(v.z - m_) : 0.f;
      float e3 = (c + 3 < NC) ? expf(v.w - m_) : 0.f;
      s_ += e0; s_ += e1; s_ += e2; s_ += e3;
      float4 st; st.x = e0; st.y = e1; st.z = e2; st.w = e3;
      *(float4*)(pr + c4 * 4) = st;
    }
    // pass3: probs back into pr; build top-16
    for (int c4 = 0; c4 < PST / 4; ++c4) {
      float4 e = *(const float4*)(pr + c4 * 4);
      int c = c4 * 4;
      float v0 = (c == 0) ? 0.f : e.x / s_;
      float v1 = (c + 1 < NC) ? e.y / s_ : 0.f;
      float v2 = (c + 2 < NC) ? e.z / s_ : 0.f;
      float v3 = (c + 3 < NC) ? e.w / s_ : 0.f;
      float4 st; st.x = v0; st.y = v1; st.z = v2; st.w = v3;
      *(float4*)(pr + c4 * 4) = st;
      if (v0 > 0.f) ins(v0, c);
      if (v1 > 0.f) ins(v1, c + 1);
      if (v2 > 0.f) ins(v2, c + 2);
      if (v3 > 0.f) ins(v3, c + 3);
    }
  } else {
    m_ = xr[0];
    for (int c = 1; c < NC; ++c) m_ = fmaxf(m_, xr[c]);
    for (int c = 0; c < NC; ++c) s_ += expf(xr[c] - m_);
    for (int c = 1; c < NC; ++c) {
      float v = expf(xr[c] - m_) / s_;
      if (v > 0.f) ins(v, c);
    }
  }

  float rowmax; int argcls; bool zstuck = false;
  if (lv[0] > 0.f) { rowmax = lv[0]; argcls = lc[0]; }
  else { rowmax = 0.f; argcls = 0; zstuck = true; }

  unsigned mask[5] = {0, 0, 0, 0, 0};
  bool retired = false;
  int post_min = INT_MAX;
  int commitcls = 0;
  int committed = 0;

  while (committed < NB) {
    cand[j] = ((ull)(unsigned)__float_as_int(rowmax) << 32) | (unsigned)(j * NC + argcls);
    __syncthreads();   // A

    // gather 512 candidates (identical in every wave)
    float vv[8]; int vi[8];
#pragma unroll
    for (int t = 0; t < 8; ++t) {
      ull k = cand[lane + 64 * t];
      vv[t] = __int_as_float((int)(k >> 32));
      vi[t] = (int)(unsigned)(k & 0xFFFFFFFFu);
    }
    float lmv = vv[0]; int lmi = vi[0];
#pragma unroll
    for (int t = 1; t < 8; ++t) if (vv[t] > lmv) { lmv = vv[t]; lmi = vi[t]; }

    // ---- exact top-16 extraction via DPP ----
    int wi16[NK];
#pragma unroll
    for (int t = 0; t < NK; ++t) wi16[t] = -1;
    unsigned okm = 0;
    int kmax = NB - committed; if (kmax > NK) kmax = NK;
    bool stop = false;
#pragma unroll
    for (int t = 0; t < NK; ++t) {
      if (t < kmax && !stop) {
        float gv = wave_max_bcast(lmv);
        ull tied = __ballot(lmv == gv);
        int gi;
        if (__popcll(tied) == 1) {
          gi = __builtin_amdgcn_readlane(lmi, (int)__ffsll(tied) - 1);
        } else {
          gi = wave_min_bcast_i((lmv == gv) ? lmi : INT_MAX);  // exact tie-break: min flat idx
        }
        wi16[t] = gi;
        if (gv > 0.f) okm |= (1u << t); else stop = true;
        if (lmi == gi) {   // owner lane pops, rescans its 8
#pragma unroll
          for (int u = 0; u < 8; ++u) if (vi[u] == gi) vv[u] = -3.0e38f;
          lmv = vv[0]; lmi = vi[0];
#pragma unroll
          for (int u = 1; u < 8; ++u) if (vv[u] > lmv) { lmv = vv[u]; lmi = vi[u]; }
        }
      }
    }

    int rows8[NK], cls8[NK];
#pragma unroll
    for (int t = 0; t < NK; ++t) {
      int idx = (wi16[t] < 0) ? 0 : wi16[t];
      int r = idx / NC;
      rows8[t] = r; cls8[t] = idx - r * NC;
    }
#pragma unroll
    for (int t = 0; t < NK; ++t) if (j == t) winlds[t] = wi16[t];

    // ---- eager per-thread overlap bits vs all 16 winners (chunks of 4) ----
    unsigned ovlmask = 0;
#pragma unroll
    for (int g = 0; g < NK / 4; ++g) {
      float4 cb[4], ob[4];
#pragma unroll
      for (int u = 0; u < 4; ++u) {
        int t = g * 4 + u;
        int idx = (wi16[t] < 0) ? 0 : wi16[t];
        cb[u] = *(const float4*)(boxes + (size_t)idx * 4);
        ob[u] = *(const float4*)(boxes + ((size_t)j * NC + cls8[t]) * 4);
      }
#pragma unroll
      for (int u = 0; u < 4; ++u) {
        int t = g * 4 + u;
        if (overlap_ge(cb[u], ob[u])) ovlmask |= (1u << t);
      }
    }
    ovlm[j] = (int)ovlmask;
    __syncthreads();   // B

    // ---- chain validity: pair (t,s) bit = thread rows8[t]'s ovl bit s ----
    const int myt = lane & 15;
    int wmt = winlds[myt];
    int wrow = (wmt < 0) ? 0 : (wmt / NC);
    int wcls = (wmt < 0) ? -1 : (wmt - wrow * NC);
    unsigned ov = (unsigned)ovlm[wrow];
    unsigned scm = 0;
#pragma unroll
    for (int s2 = 0; s2 < NK; ++s2) {
      if (s2 < myt && cls8[s2] == wcls) scm |= (1u << s2);
    }
    unsigned confmask = ov & scm;

    unsigned validset = 1; int p = 1;
#pragma unroll
    for (int t = 1; t < NK; ++t) {
      unsigned cm = (unsigned)__builtin_amdgcn_readlane((int)confmask, t);
      if (p == t && ((okm >> t) & 1u) && ((cm & validset) == 0u)) {
        validset |= (1u << t); p = t + 1;
      }
    }

    // ---- apply the p commits in order ----
#pragma unroll
    for (int t = 0; t < NK; ++t) {
      if (t < p) {
        if (j == rows8[t]) {
          // commit: col update overwritten by row := -1 (reference order)
          retired = true; commitcls = cls8[t]; post_min = INT_MAX;
        } else if ((ovlmask >> t) & 1u) {
          if (retired) {
            post_min = (cls8[t] < post_min) ? cls8[t] : post_min;  // resurrect -1 -> 0.0
          } else {
            int c = cls8[t];
#pragma unroll
            for (int k5 = 0; k5 < 5; ++k5) if (k5 == (c >> 5)) mask[k5] |= (1u << (c & 31));
          }
        }
      }
    }

    // ---- recompute my candidate ----
    if (retired) {
      rowmax = (post_min != INT_MAX) ? 0.0f : -1.0f;
      argcls = (post_min != INT_MAX) ? post_min : 0;
    } else if (!zstuck) {
      bool found = false;
#pragma unroll
      for (int t = 0; t < NK; ++t) {
        if (!found && lv[t] > 0.f && !mbit(mask, lc[t])) {
          rowmax = lv[t]; argcls = lc[t]; found = true;
        }
      }
      if (!found) {
        // rare: full rescan (exact values) + list refill
        float bm = -3.4e38f; int ba = 0;
#pragma unroll
        for (int t = 0; t < NK; ++t) { lv[t] = -3.4e38f; lc[t] = 0; }
        if (USEWS) {
          for (int c4 = 0; c4 < PST / 4; ++c4) {
            float4 v4 = *(const float4*)(pr + c4 * 4);
            int c = c4 * 4;
            float vals[4] = {v4.x, v4.y, v4.z, v4.w};
#pragma unroll
            for (int u = 0; u < 4; ++u) {
              int cc = c + u;
              if (cc < NC) {
                float v = mbit(mask, cc) ? 0.f : vals[u];   // pr already 0 at c==0
                if (v > bm) { bm = v; ba = cc; }
                if (v > 0.f) ins(v, cc);
              }
            }
          }
        } else {
          for (int c = 0; c < NC; ++c) {
            float v;
            if (c == 0) v = 0.f;
            else v = mbit(mask, c) ? 0.f : (expf(xr[c] - m_) / s_);
            if (v > bm) { bm = v; ba = c; }
            if (v > 0.f) ins(v, c);
          }
        }
        rowmax = bm; argcls = ba;
        if (!(bm > 0.f)) zstuck = true;   // all zero: stable at (0.0, argmax c) forever
      }
    }
    // zstuck: keep (rowmax, argcls) — values can never increase for this row

    committed += p;
  }

  commits[j] = (float)commitcls;
}

extern "C" void kernel_launch(void* const* d_in, const int* in_sizes, int n_in,
                              void* d_out, int out_size, void* d_ws, size_t ws_size,
                              hipStream_t stream) {
  const float* A     = (const float*)d_in[0];   // obj_fmap [512,4096]
  const float* boxes = (const float*)d_in[1];   // boxes_per_cls [512,151,4]
  const float* W     = (const float*)d_in[2];   // [4096,151]
  const float* bias  = (const float*)d_in[3];   // [151]
  float* out = (float*)d_out;                   // [512*151] obj_dists ++ [512] commits

  const size_t need = (size_t)(KS * NB + NB) * PST * 4;
  if (ws_size >= need) {
    float* part  = (float*)d_ws;
    float* probs = part + (size_t)KS * NB * PST;
    gemm_partial<<<dim3(NB / GRB, KS), 192, 0, stream>>>(A, W, part);
    decode_kernel<true><<<1, NB, 0, stream>>>(part, bias, boxes, probs, out + NB * NC);
    reduce_out<<<(NB * NC + 255) / 256, 256, 0, stream>>>(part, bias, out);
  } else {
    gemm_full<<<NB / 4, 192, 0, stream>>>(A, W, bias, out);
    decode_kernel<false><<<1, NB, 0, stream>>>(out, nullptr, boxes, nullptr, out + NB * NC);
  }
}

// Round 5
// 773.347 us; speedup vs baseline: 1.0585x; 1.0585x over previous
//
#include <hip/hip_runtime.h>
#include <limits.h>

#pragma clang fp contract(off)

#define NB 512
#define NC 151
#define KDIM 4096
#define KS 8
#define KCH (KDIM/KS)      // 512
#define GRB 16             // gemm rows per block
#define PST 152            // padded row stride (floats), 16B-aligned rows
#define NMS_TH 0.3f

typedef unsigned long long ull;

// ---------------- DPP wave64 reductions ----------------
template <int CTRL>
__device__ __forceinline__ int dpp_i(int identity, int x) {
  return __builtin_amdgcn_update_dpp(identity, x, CTRL, 0xF, 0xF, false);
}
__device__ __forceinline__ float wave_max_bcast(float x) {
  const int ID = __float_as_int(-3.4e38f);
  x = fmaxf(x, __int_as_float(dpp_i<0x111>(ID, __float_as_int(x))));  // row_shr:1
  x = fmaxf(x, __int_as_float(dpp_i<0x112>(ID, __float_as_int(x))));  // row_shr:2
  x = fmaxf(x, __int_as_float(dpp_i<0x114>(ID, __float_as_int(x))));  // row_shr:4
  x = fmaxf(x, __int_as_float(dpp_i<0x118>(ID, __float_as_int(x))));  // row_shr:8
  x = fmaxf(x, __int_as_float(dpp_i<0x142>(ID, __float_as_int(x))));  // row_bcast:15
  x = fmaxf(x, __int_as_float(dpp_i<0x143>(ID, __float_as_int(x))));  // row_bcast:31
  return __int_as_float(__builtin_amdgcn_readlane(__float_as_int(x), 63));
}
__device__ __forceinline__ int wave_min_bcast_i(int x) {
  int y;
  y = dpp_i<0x111>(INT_MAX, x); x = (x < y) ? x : y;
  y = dpp_i<0x112>(INT_MAX, x); x = (x < y) ? x : y;
  y = dpp_i<0x114>(INT_MAX, x); x = (x < y) ? x : y;
  y = dpp_i<0x118>(INT_MAX, x); x = (x < y) ? x : y;
  y = dpp_i<0x142>(INT_MAX, x); x = (x < y) ? x : y;
  y = dpp_i<0x143>(INT_MAX, x); x = (x < y) ? x : y;
  return __builtin_amdgcn_readlane(x, 63);
}

// exact reference IoU arithmetic (fp contract off file-wide)
__device__ __forceinline__ bool overlap_ge(const float4& c, const float4& o) {
  float areaC = (c.z - c.x + 1.0f) * (c.w - c.y + 1.0f);
  float areaJ = (o.z - o.x + 1.0f) * (o.w - o.y + 1.0f);
  float iw = fminf(c.z, o.z) - fmaxf(c.x, o.x) + 1.0f;
  float ih = fminf(c.w, o.w) - fmaxf(c.y, o.y) + 1.0f;
  iw = fmaxf(iw, 0.0f); ih = fmaxf(ih, 0.0f);
  float inter = iw * ih;
  float uni = areaC + areaJ - inter;
  return inter / uni >= NMS_TH;
}

__device__ __forceinline__ bool mbit(const unsigned m[5], int c) {
  bool r = false;
#pragma unroll
  for (int k = 0; k < 5; ++k) r = (k == (c >> 5)) ? (((m[k] >> (c & 31)) & 1u) != 0) : r;
  return r;
}

// ---------------- GEMM split-K partials (round-3 LDS version, PST stride) ----------------
__global__ __launch_bounds__(192) void gemm_partial(
    const float* __restrict__ A, const float* __restrict__ W, float* __restrict__ part)
{
  __shared__ float sA[GRB * KCH];  // 32 KB
  int rb = blockIdx.x, ks = blockIdx.y;
  const float* Ab = A + (size_t)rb * GRB * KDIM + (size_t)ks * KCH;
  for (int i = threadIdx.x; i < GRB * (KCH / 4); i += 192) {
    int r = i >> 7;            // KCH/4 = 128
    int k4 = i & 127;
    *(float4*)(sA + r * KCH + k4 * 4) = *(const float4*)(Ab + (size_t)r * KDIM + k4 * 4);
  }
  __syncthreads();
  int c = threadIdx.x;
  if (c < NC) {
    const float* wp = W + (size_t)ks * KCH * NC + c;
    float acc[GRB];
#pragma unroll
    for (int r = 0; r < GRB; ++r) acc[r] = 0.f;
    for (int k4 = 0; k4 < KCH / 4; ++k4) {
      float w0 = wp[(size_t)(4 * k4 + 0) * NC];
      float w1 = wp[(size_t)(4 * k4 + 1) * NC];
      float w2 = wp[(size_t)(4 * k4 + 2) * NC];
      float w3 = wp[(size_t)(4 * k4 + 3) * NC];
#pragma unroll
      for (int r = 0; r < GRB; ++r) {
        float4 a = *(const float4*)(sA + r * KCH + k4 * 4);  // broadcast read
        acc[r] = fmaf(a.x, w0, acc[r]);
        acc[r] = fmaf(a.y, w1, acc[r]);
        acc[r] = fmaf(a.z, w2, acc[r]);
        acc[r] = fmaf(a.w, w3, acc[r]);
      }
    }
    float* o = part + ((size_t)ks * NB + (size_t)rb * GRB) * PST + c;
#pragma unroll
    for (int r = 0; r < GRB; ++r) o[(size_t)r * PST] = acc[r];
  }
}

// fallback (ws too small)
__global__ __launch_bounds__(192) void gemm_full(
    const float* __restrict__ A, const float* __restrict__ W,
    const float* __restrict__ bias, float* __restrict__ out)
{
  int c = threadIdx.x;
  int r0 = blockIdx.x * 4;
  if (c >= NC) return;
  const float* a = A + (size_t)r0 * KDIM;
  const float* wp = W + c;
  float a0 = 0.f, a1 = 0.f, a2 = 0.f, a3 = 0.f;
#pragma unroll 8
  for (int k = 0; k < KDIM; ++k) {
    float w = wp[(size_t)k * NC];
    a0 = fmaf(a[k],            w, a0);
    a1 = fmaf(a[k + KDIM],     w, a1);
    a2 = fmaf(a[k + 2 * KDIM], w, a2);
    a3 = fmaf(a[k + 3 * KDIM], w, a3);
  }
  float bb = bias[c];
  out[(size_t)(r0 + 0) * NC + c] = a0 + bb;
  out[(size_t)(r0 + 1) * NC + c] = a1 + bb;
  out[(size_t)(r0 + 2) * NC + c] = a2 + bb;
  out[(size_t)(r0 + 3) * NC + c] = a3 + bb;
}

// ---------------- Multi-commit greedy NMS decode (NK=8, round-3 skeleton) ----------------
// USEWS: src = partials [KS][NB][PST]; phase A also writes obj_dists to outd and
//        exact probs to probsws [NB][PST] so rescans are float4 reads, no expf.
template <bool USEWS>
__global__ __launch_bounds__(512) void decode_kernel(
    const float* __restrict__ src, const float* __restrict__ bias,
    const float* __restrict__ boxes, float* __restrict__ probsws,
    float* __restrict__ outd, float* __restrict__ commits)
{
  __shared__ ull cand[2][NB];   // 8 KB, double-buffered
  const int j = threadIdx.x;
  const int lane = j & 63;

  // ---- per-row top-8 list (stable desc) ----
  float lv[8]; int lc[8];
#pragma unroll
  for (int t = 0; t < 8; ++t) { lv[t] = -3.4e38f; lc[t] = 0; }
  auto ins = [&](float v, int c) {
    if (v > lv[7]) {
      lv[7] = v; lc[7] = c;
#pragma unroll
      for (int q = 7; q > 0; --q) {
        if (lv[q] > lv[q - 1]) {
          float tv = lv[q]; lv[q] = lv[q - 1]; lv[q - 1] = tv;
          int tc = lc[q]; lc[q] = lc[q - 1]; lc[q - 1] = tc;
        }
      }
    }
  };

  float m_ = -3.4e38f, s_ = 0.f;
  const float* xr = USEWS ? nullptr : (src + (size_t)j * NC);
  float* pr = USEWS ? (probsws + (size_t)j * PST) : nullptr;

  if (USEWS) {
    float* orow = outd + (size_t)j * NC;
    // pass1: sum split-K partials + bias -> logits into pr AND obj_dists out
    for (int c4 = 0; c4 < PST / 4; ++c4) {
      float x0 = 0.f, x1 = 0.f, x2 = 0.f, x3 = 0.f;
#pragma unroll
      for (int ks = 0; ks < KS; ++ks) {
        const float4 v = *(const float4*)(src + ((size_t)ks * NB + j) * PST + c4 * 4);
        x0 += v.x; x1 += v.y; x2 += v.z; x3 += v.w;
      }
      int c = c4 * 4;
      x0 += bias[c];
      if (c + 1 < NC) x1 += bias[c + 1];
      if (c + 2 < NC) x2 += bias[c + 2];
      if (c + 3 < NC) x3 += bias[c + 3];
      float4 st; st.x = x0; st.y = x1; st.z = x2; st.w = x3;
      *(float4*)(pr + c4 * 4) = st;
      orow[c] = x0;
      if (c + 1 < NC) orow[c + 1] = x1;
      if (c + 2 < NC) orow[c + 2] = x2;
      if (c + 3 < NC) orow[c + 3] = x3;
      m_ = fmaxf(m_, x0);
      if (c + 1 < NC) m_ = fmaxf(m_, x1);
      if (c + 2 < NC) m_ = fmaxf(m_, x2);
      if (c + 3 < NC) m_ = fmaxf(m_, x3);
    }
    // pass2: exp into pr; accumulate s ascending
    for (int c4 = 0; c4 < PST / 4; ++c4) {
      float4 v = *(const float4*)(pr + c4 * 4);
      int c = c4 * 4;
      float e0 = expf(v.x - m_);
      float e1 = (c + 1 < NC) ? expf(v.y - m_) : 0.f;
      float e2 = (c + 2 < NC) ? expf(v.z - m_) : 0.f;
      float e3 = (c + 3 < NC) ? expf(v.w - m_) : 0.f;
      s_ += e0; s_ += e1; s_ += e2; s_ += e3;
      float4 st; st.x = e0; st.y = e1; st.z = e2; st.w = e3;
      *(float4*)(pr + c4 * 4) = st;
    }
    // pass3: probs into pr; build top-8
    for (int c4 = 0; c4 < PST / 4; ++c4) {
      float4 e = *(const float4*)(pr + c4 * 4);
      int c = c4 * 4;
      float v0 = (c == 0) ? 0.f : e.x / s_;
      float v1 = (c + 1 < NC) ? e.y / s_ : 0.f;
      float v2 = (c + 2 < NC) ? e.z / s_ : 0.f;
      float v3 = (c + 3 < NC) ? e.w / s_ : 0.f;
      float4 st; st.x = v0; st.y = v1; st.z = v2; st.w = v3;
      *(float4*)(pr + c4 * 4) = st;
      if (v0 > 0.f) ins(v0, c);
      if (v1 > 0.f) ins(v1, c + 1);
      if (v2 > 0.f) ins(v2, c + 2);
      if (v3 > 0.f) ins(v3, c + 3);
    }
  } else {
    m_ = xr[0];
    for (int c = 1; c < NC; ++c) m_ = fmaxf(m_, xr[c]);
    for (int c = 0; c < NC; ++c) s_ += expf(xr[c] - m_);
    for (int c = 1; c < NC; ++c) {
      float v = expf(xr[c] - m_) / s_;
      if (v > 0.f) ins(v, c);
    }
  }

  float rowmax; int argcls; bool zstuck = false;
  if (lv[0] > 0.f) { rowmax = lv[0]; argcls = lc[0]; }
  else { rowmax = 0.f; argcls = 0; zstuck = true; }

  unsigned mask[5] = {0, 0, 0, 0, 0};
  bool retired = false;
  int post_min = INT_MAX;
  int commitcls = 0;
  int committed = 0;
  int par = 0;

  while (committed < NB) {
    cand[par][j] = ((ull)(unsigned)__float_as_int(rowmax) << 32) | (unsigned)(j * NC + argcls);
    __syncthreads();

    // gather all 512 candidates (identical in every wave)
    float vv[8]; int vi[8];
#pragma unroll
    for (int t = 0; t < 8; ++t) {
      ull k = cand[par][lane + 64 * t];
      vv[t] = __int_as_float((int)(k >> 32));
      vi[t] = (int)(unsigned)(k & 0xFFFFFFFFu);
    }
    float lmv = vv[0]; int lmi = vi[0];
#pragma unroll
    for (int t = 1; t < 8; ++t) if (vv[t] > lmv) { lmv = vv[t]; lmi = vi[t]; }

    // ---- exact top-8 extraction via DPP ----
    float wv[8]; int wi[8];
    int kmax = NB - committed; if (kmax > 8) kmax = 8;
    bool stop = false;
#pragma unroll
    for (int t = 0; t < 8; ++t) {
      if (t >= kmax || stop) { wi[t] = -1; wv[t] = -1.f; continue; }
      float gv = wave_max_bcast(lmv);
      ull tied = __ballot(lmv == gv);
      int gi;
      if (__popcll(tied) == 1) {
        gi = __builtin_amdgcn_readlane(lmi, (int)__ffsll(tied) - 1);
      } else {
        gi = wave_min_bcast_i((lmv == gv) ? lmi : INT_MAX);  // exact min-flat-idx tie-break
      }
      wv[t] = gv; wi[t] = gi;
      if (lmi == gi) {   // winner lane pops and rescans its 8
#pragma unroll
        for (int u = 0; u < 8; ++u) if (vi[u] == gi) vv[u] = -3.0e38f;
        lmv = vv[0]; lmi = vi[0];
#pragma unroll
        for (int u = 1; u < 8; ++u) if (vv[u] > lmv) { lmv = vv[u]; lmi = vi[u]; }
      }
      if (!(gv > 0.0f)) stop = true;   // value <= 0: nothing beyond can chain
    }

    // decode rows/classes (wave-uniform scalars)
    int rows8[8], cls8[8]; unsigned okm = 0;
#pragma unroll
    for (int t = 0; t < 8; ++t) {
      int idx = (wi[t] < 0) ? 0 : wi[t];
      int r = idx / NC;
      rows8[t] = r; cls8[t] = idx - r * NC;
      if (wi[t] >= 0 && wv[t] > 0.f) okm |= (1u << t);
    }

    // ---- pairwise chain validity: lane (t,s) = (lane>>3, lane&7), s<t ----
    int lt = lane >> 3, ls = lane & 7;
    int iT = wi[0], iS = wi[0], cT = cls8[0], cS = cls8[0];
#pragma unroll
    for (int t = 1; t < 8; ++t) {
      iT = (lt == t) ? wi[t]   : iT;  cT = (lt == t) ? cls8[t] : cT;
      iS = (ls == t) ? wi[t]   : iS;  cS = (ls == t) ? cls8[t] : cS;
    }
    bool sup = false;
    if (ls < lt && ((okm >> lt) & 1) && ((okm >> ls) & 1) && cT == cS && iT >= 0 && iS >= 0) {
      float4 bs = *(const float4*)(boxes + (size_t)iS * 4);  // earlier commit
      float4 bt = *(const float4*)(boxes + (size_t)iT * 4);
      sup = overlap_ge(bs, bt);
    }
    ull B = __ballot(sup);   // bit (8*t + s); identical in every wave
    unsigned validset = 1; int p = 1;
#pragma unroll
    for (int t = 1; t < 8; ++t) {
      if (p == t && ((okm >> t) & 1) && (((B >> (8 * t)) & (ull)validset) == 0)) {
        validset |= (1u << t); p = t + 1;
      }
    }

    // ---- all threads: apply the p commits in order ----
    float4 cb[8], ob[8];
#pragma unroll
    for (int t = 0; t < 8; ++t) if (t < p) {
      cb[t] = *(const float4*)(boxes + (size_t)wi[t] * 4);                 // uniform
      ob[t] = *(const float4*)(boxes + ((size_t)j * NC + cls8[t]) * 4);
    }
#pragma unroll
    for (int t = 0; t < 8; ++t) if (t < p) {
      if (j == rows8[t]) {
        // commit: col update overwritten by row := -1 (reference order)
        retired = true; commitcls = cls8[t]; post_min = INT_MAX;
      } else if (overlap_ge(cb[t], ob[t])) {
        if (retired) {
          post_min = (cls8[t] < post_min) ? cls8[t] : post_min;  // resurrect -1 -> 0.0
        } else {
          int c = cls8[t];
#pragma unroll
          for (int k5 = 0; k5 < 5; ++k5) if (k5 == (c >> 5)) mask[k5] |= (1u << (c & 31));
        }
      }
    }

    // ---- recompute my candidate ----
    if (retired) {
      rowmax = (post_min != INT_MAX) ? 0.0f : -1.0f;
      argcls = (post_min != INT_MAX) ? post_min : 0;
    } else if (!zstuck) {
      bool found = false;
#pragma unroll
      for (int t = 0; t < 8; ++t) {
        if (!found && lv[t] > 0.f && !mbit(mask, lc[t])) {
          rowmax = lv[t]; argcls = lc[t]; found = true;
        }
      }
      if (!found) {
        // rare: full rescan with list refill (no expf in USEWS path)
        float bm = -3.4e38f; int ba = 0;
#pragma unroll
        for (int t = 0; t < 8; ++t) { lv[t] = -3.4e38f; lc[t] = 0; }
        if (USEWS) {
          for (int c4 = 0; c4 < PST / 4; ++c4) {
            float4 v4 = *(const float4*)(pr + c4 * 4);
            int c = c4 * 4;
            float vals[4] = {v4.x, v4.y, v4.z, v4.w};
#pragma unroll
            for (int u = 0; u < 4; ++u) {
              int cc = c + u;
              if (cc < NC) {
                float v = mbit(mask, cc) ? 0.f : vals[u];   // pr already 0 at c==0
                if (v > bm) { bm = v; ba = cc; }
                if (v > 0.f) ins(v, cc);
              }
            }
          }
        } else {
          for (int c = 0; c < NC; ++c) {
            float v;
            if (c == 0) v = 0.f;
            else v = mbit(mask, c) ? 0.f : (expf(xr[c] - m_) / s_);
            if (v > bm) { bm = v; ba = c; }
            if (v > 0.f) ins(v, c);
          }
        }
        rowmax = bm; argcls = ba;
        if (!(bm > 0.f)) zstuck = true;   // all-zero row: candidate stable forever
      }
    }
    // zstuck: keep (rowmax, argcls) — values can never increase for this row

    committed += p;
    par ^= 1;
  }

  commits[j] = (float)commitcls;
}

extern "C" void kernel_launch(void* const* d_in, const int* in_sizes, int n_in,
                              void* d_out, int out_size, void* d_ws, size_t ws_size,
                              hipStream_t stream) {
  const float* A     = (const float*)d_in[0];   // obj_fmap [512,4096]
  const float* boxes = (const float*)d_in[1];   // boxes_per_cls [512,151,4]
  const float* W     = (const float*)d_in[2];   // [4096,151]
  const float* bias  = (const float*)d_in[3];   // [151]
  float* out = (float*)d_out;                   // [512*151] obj_dists ++ [512] commits

  const size_t need = (size_t)(KS * NB + NB) * PST * 4;
  if (ws_size >= need) {
    float* part  = (float*)d_ws;
    float* probs = part + (size_t)KS * NB * PST;
    gemm_partial<<<dim3(NB / GRB, KS), 192, 0, stream>>>(A, W, part);
    decode_kernel<true><<<1, NB, 0, stream>>>(part, bias, boxes, probs, out, out + NB * NC);
  } else {
    gemm_full<<<NB / 4, 192, 0, stream>>>(A, W, bias, out);
    decode_kernel<false><<<1, NB, 0, stream>>>(out, nullptr, boxes, nullptr, out, out + NB * NC);
  }
}

// Round 6
// 616.389 us; speedup vs baseline: 1.3280x; 1.2546x over previous
//
#include <hip/hip_runtime.h>
#include <limits.h>

#pragma clang fp contract(off)

#define NB 512
#define NC 151
#define KDIM 4096
#define KS 8
#define KCH (KDIM/KS)      // 512
#define GRB 16             // gemm rows per block
#define PST 152            // padded row stride (floats), 16B-aligned rows
#define NMS_TH 0.3f

typedef unsigned long long ull;

// ---------------- DPP wave64 reductions ----------------
template <int CTRL>
__device__ __forceinline__ int dpp_i(int identity, int x) {
  return __builtin_amdgcn_update_dpp(identity, x, CTRL, 0xF, 0xF, false);
}
__device__ __forceinline__ float wave_max_bcast(float x) {
  const int ID = __float_as_int(-3.4e38f);
  x = fmaxf(x, __int_as_float(dpp_i<0x111>(ID, __float_as_int(x))));  // row_shr:1
  x = fmaxf(x, __int_as_float(dpp_i<0x112>(ID, __float_as_int(x))));  // row_shr:2
  x = fmaxf(x, __int_as_float(dpp_i<0x114>(ID, __float_as_int(x))));  // row_shr:4
  x = fmaxf(x, __int_as_float(dpp_i<0x118>(ID, __float_as_int(x))));  // row_shr:8
  x = fmaxf(x, __int_as_float(dpp_i<0x142>(ID, __float_as_int(x))));  // row_bcast:15
  x = fmaxf(x, __int_as_float(dpp_i<0x143>(ID, __float_as_int(x))));  // row_bcast:31
  return __int_as_float(__builtin_amdgcn_readlane(__float_as_int(x), 63));
}
__device__ __forceinline__ int wave_min_bcast_i(int x) {
  int y;
  y = dpp_i<0x111>(INT_MAX, x); x = (x < y) ? x : y;
  y = dpp_i<0x112>(INT_MAX, x); x = (x < y) ? x : y;
  y = dpp_i<0x114>(INT_MAX, x); x = (x < y) ? x : y;
  y = dpp_i<0x118>(INT_MAX, x); x = (x < y) ? x : y;
  y = dpp_i<0x142>(INT_MAX, x); x = (x < y) ? x : y;
  y = dpp_i<0x143>(INT_MAX, x); x = (x < y) ? x : y;
  return __builtin_amdgcn_readlane(x, 63);
}

// exact reference IoU arithmetic (fp contract off file-wide)
__device__ __forceinline__ bool overlap_ge(const float4& c, const float4& o) {
  float areaC = (c.z - c.x + 1.0f) * (c.w - c.y + 1.0f);
  float areaJ = (o.z - o.x + 1.0f) * (o.w - o.y + 1.0f);
  float iw = fminf(c.z, o.z) - fmaxf(c.x, o.x) + 1.0f;
  float ih = fminf(c.w, o.w) - fmaxf(c.y, o.y) + 1.0f;
  iw = fmaxf(iw, 0.0f); ih = fmaxf(ih, 0.0f);
  float inter = iw * ih;
  float uni = areaC + areaJ - inter;
  return inter / uni >= NMS_TH;
}

__device__ __forceinline__ bool mbit(const unsigned m[5], int c) {
  bool r = false;
#pragma unroll
  for (int k = 0; k < 5; ++k) r = (k == (c >> 5)) ? (((m[k] >> (c & 31)) & 1u) != 0) : r;
  return r;
}

// ---------------- GEMM split-K partials (LDS staging + W prefetch) ----------------
__global__ __launch_bounds__(192) void gemm_partial(
    const float* __restrict__ A, const float* __restrict__ W, float* __restrict__ part)
{
  __shared__ float sA[GRB * KCH];  // 32 KB
  int rb = blockIdx.x, ks = blockIdx.y;
  const float* Ab = A + (size_t)rb * GRB * KDIM + (size_t)ks * KCH;
  for (int i = threadIdx.x; i < GRB * (KCH / 4); i += 192) {
    int r = i >> 7;            // KCH/4 = 128
    int k4 = i & 127;
    *(float4*)(sA + r * KCH + k4 * 4) = *(const float4*)(Ab + (size_t)r * KDIM + k4 * 4);
  }
  __syncthreads();
  int c = threadIdx.x;
  if (c < NC) {
    const float* wp = W + (size_t)ks * KCH * NC + c;
    float acc[GRB];
#pragma unroll
    for (int r = 0; r < GRB; ++r) acc[r] = 0.f;
    float w0 = wp[0], w1 = wp[NC], w2 = wp[2 * NC], w3 = wp[3 * NC];
    for (int k4 = 0; k4 < KCH / 4; ++k4) {
      int kn = (k4 + 1 < KCH / 4) ? (k4 + 1) : k4;     // clamp: re-read last (no OOB)
      const float* q = wp + (size_t)(4 * kn) * NC;
      float n0 = q[0], n1 = q[NC], n2 = q[2 * NC], n3 = q[3 * NC];
#pragma unroll
      for (int r = 0; r < GRB; ++r) {
        float4 a = *(const float4*)(sA + r * KCH + k4 * 4);  // broadcast read
        acc[r] = fmaf(a.x, w0, acc[r]);
        acc[r] = fmaf(a.y, w1, acc[r]);
        acc[r] = fmaf(a.z, w2, acc[r]);
        acc[r] = fmaf(a.w, w3, acc[r]);
      }
      w0 = n0; w1 = n1; w2 = n2; w3 = n3;
    }
    float* o = part + ((size_t)ks * NB + (size_t)rb * GRB) * PST + c;
#pragma unroll
    for (int r = 0; r < GRB; ++r) o[(size_t)r * PST] = acc[r];
  }
}

// parallel finish: obj_dists -> out, padded logits (-inf pad) -> lp (ws)
__global__ void gemm_reduce(const float* __restrict__ part, const float* __restrict__ bias,
                            float* __restrict__ out, float* __restrict__ lp) {
  int i = blockIdx.x * 256 + threadIdx.x;
  if (i >= NB * PST) return;
  int r = i / PST, c = i - r * PST;
  float acc = 0.f;
#pragma unroll
  for (int ks = 0; ks < KS; ++ks) acc += part[((size_t)ks * NB + r) * PST + c];
  float val;
  if (c < NC) { val = acc + bias[c]; out[(size_t)r * NC + c] = val; }
  else val = -3.4e38f;
  lp[i] = val;
}

// fallback (ws too small)
__global__ __launch_bounds__(192) void gemm_full(
    const float* __restrict__ A, const float* __restrict__ W,
    const float* __restrict__ bias, float* __restrict__ out)
{
  int c = threadIdx.x;
  int r0 = blockIdx.x * 4;
  if (c >= NC) return;
  const float* a = A + (size_t)r0 * KDIM;
  const float* wp = W + c;
  float a0 = 0.f, a1 = 0.f, a2 = 0.f, a3 = 0.f;
#pragma unroll 8
  for (int k = 0; k < KDIM; ++k) {
    float w = wp[(size_t)k * NC];
    a0 = fmaf(a[k],            w, a0);
    a1 = fmaf(a[k + KDIM],     w, a1);
    a2 = fmaf(a[k + 2 * KDIM], w, a2);
    a3 = fmaf(a[k + 3 * KDIM], w, a3);
  }
  float bb = bias[c];
  out[(size_t)(r0 + 0) * NC + c] = a0 + bb;
  out[(size_t)(r0 + 1) * NC + c] = a1 + bb;
  out[(size_t)(r0 + 2) * NC + c] = a2 + bb;
  out[(size_t)(r0 + 3) * NC + c] = a3 + bb;
}

// ---------------- Multi-commit greedy NMS decode ----------------
// Round: all write candidate -> barrier A -> WAVE 0 ONLY extracts exact top-8
// (DPP) + chain validity + prefix, publishes via LDS -> barrier B -> all
// threads apply p commits + recompute candidate (top-8 list w/ refill rescan).
// USEWS: src = padded logits [NB][PST] (-inf pad); else src = obj_dists [NB][NC].
template <bool USEWS>
__global__ __launch_bounds__(512) void decode_kernel(
    const float* __restrict__ src, const float* __restrict__ boxes,
    float* __restrict__ commits)
{
  __shared__ ull cand[NB];    // 4 KB
  __shared__ int swin[8];
  __shared__ int s_p;
  const int j = threadIdx.x;
  const int lane = j & 63;
  const float* xr = USEWS ? (src + (size_t)j * PST) : (src + (size_t)j * NC);

  // ---- phase A: softmax constants + per-row top-8 (stable desc) ----
  float lv[8]; int lc[8];
#pragma unroll
  for (int t = 0; t < 8; ++t) { lv[t] = -3.4e38f; lc[t] = 0; }
  auto ins = [&](float v, int c) {
    if (v > lv[7]) {
      lv[7] = v; lc[7] = c;
#pragma unroll
      for (int q = 7; q > 0; --q) {
        if (lv[q] > lv[q - 1]) {
          float tv = lv[q]; lv[q] = lv[q - 1]; lv[q - 1] = tv;
          int tc = lc[q]; lc[q] = lc[q - 1]; lc[q - 1] = tc;
        }
      }
    }
  };

  float m_ = -3.4e38f, s_ = 0.f;
  if (USEWS) {
    for (int c4 = 0; c4 < PST / 4; ++c4) {
      float4 v = *(const float4*)(xr + c4 * 4);
      m_ = fmaxf(fmaxf(fmaxf(m_, v.x), fmaxf(v.y, v.z)), v.w);   // pad=-inf never wins
    }
    for (int c4 = 0; c4 < PST / 4; ++c4) {
      float4 v = *(const float4*)(xr + c4 * 4);
      s_ += expf(v.x - m_); s_ += expf(v.y - m_);
      s_ += expf(v.z - m_); s_ += expf(v.w - m_);                // pad contributes exp(-inf)=0
    }
    for (int c4 = 0; c4 < PST / 4; ++c4) {
      float4 v = *(const float4*)(xr + c4 * 4);
      int c = c4 * 4;
      float p0 = (c == 0) ? 0.f : expf(v.x - m_) / s_;
      float p1 = expf(v.y - m_) / s_;
      float p2 = expf(v.z - m_) / s_;
      float p3 = expf(v.w - m_) / s_;
      if (p0 > 0.f) ins(p0, c);
      if (p1 > 0.f) ins(p1, c + 1);
      if (p2 > 0.f) ins(p2, c + 2);
      if (p3 > 0.f) ins(p3, c + 3);                              // pad p=0 -> skipped
    }
  } else {
    m_ = xr[0];
    for (int c = 1; c < NC; ++c) m_ = fmaxf(m_, xr[c]);
    for (int c = 0; c < NC; ++c) s_ += expf(xr[c] - m_);
    for (int c = 1; c < NC; ++c) {
      float v = expf(xr[c] - m_) / s_;
      if (v > 0.f) ins(v, c);
    }
  }

  float rowmax; int argcls; bool zstuck = false;
  if (lv[0] > 0.f) { rowmax = lv[0]; argcls = lc[0]; }
  else { rowmax = 0.f; argcls = 0; zstuck = true; }

  unsigned mask[5] = {0, 0, 0, 0, 0};
  bool retired = false;
  int post_min = INT_MAX;
  int commitcls = 0;
  int committed = 0;

  while (committed < NB) {
    cand[j] = ((ull)(unsigned)__float_as_int(rowmax) << 32) | (unsigned)(j * NC + argcls);
    __syncthreads();   // A

    if (j < 64) {
      // ---- wave 0 only: gather + exact top-8 extraction + validity + prefix ----
      float vv[8]; int vi[8];
#pragma unroll
      for (int t = 0; t < 8; ++t) {
        ull k = cand[lane + 64 * t];
        vv[t] = __int_as_float((int)(k >> 32));
        vi[t] = (int)(unsigned)(k & 0xFFFFFFFFu);
      }
      float lmv = vv[0]; int lmi = vi[0];
#pragma unroll
      for (int t = 1; t < 8; ++t) if (vv[t] > lmv) { lmv = vv[t]; lmi = vi[t]; }

      int wi[8]; unsigned okm = 0;
      int kmax = NB - committed; if (kmax > 8) kmax = 8;
      bool stop = false;
#pragma unroll
      for (int t = 0; t < 8; ++t) {
        if (t >= kmax || stop) { wi[t] = -1; continue; }
        float gv = wave_max_bcast(lmv);
        ull tied = __ballot(lmv == gv);
        int gi;
        if (__popcll(tied) == 1) {
          gi = __builtin_amdgcn_readlane(lmi, (int)__ffsll(tied) - 1);
        } else {
          gi = wave_min_bcast_i((lmv == gv) ? lmi : INT_MAX);  // exact min-flat-idx tie-break
        }
        wi[t] = gi;
        if (gv > 0.f) okm |= (1u << t); else stop = true;
        if (lmi == gi) {   // winner lane pops and rescans its 8
#pragma unroll
          for (int u = 0; u < 8; ++u) if (vi[u] == gi) vv[u] = -3.0e38f;
          lmv = vv[0]; lmi = vi[0];
#pragma unroll
          for (int u = 1; u < 8; ++u) if (vv[u] > lmv) { lmv = vv[u]; lmi = vi[u]; }
        }
      }

      int cls8[8];
#pragma unroll
      for (int t = 0; t < 8; ++t) {
        int idx = (wi[t] < 0) ? 0 : wi[t];
        cls8[t] = idx - (idx / NC) * NC;
      }

      // pairwise validity: lane (t,s) = (lane>>3, lane&7), s<t
      int lt = lane >> 3, ls = lane & 7;
      int iT = wi[0], iS = wi[0], cT = cls8[0], cS = cls8[0];
#pragma unroll
      for (int t = 1; t < 8; ++t) {
        iT = (lt == t) ? wi[t]   : iT;  cT = (lt == t) ? cls8[t] : cT;
        iS = (ls == t) ? wi[t]   : iS;  cS = (ls == t) ? cls8[t] : cS;
      }
      bool sup = false;
      if (ls < lt && ((okm >> lt) & 1) && ((okm >> ls) & 1) && cT == cS && iT >= 0 && iS >= 0) {
        float4 bs = *(const float4*)(boxes + (size_t)iS * 4);  // earlier commit
        float4 bt = *(const float4*)(boxes + (size_t)iT * 4);
        sup = overlap_ge(bs, bt);
      }
      ull B = __ballot(sup);   // bit (8*t + s)
      unsigned validset = 1; int p = 1;
#pragma unroll
      for (int t = 1; t < 8; ++t) {
        if (p == t && ((okm >> t) & 1) && (((B >> (8 * t)) & (ull)validset) == 0)) {
          validset |= (1u << t); p = t + 1;
        }
      }

      int sv = wi[0];
#pragma unroll
      for (int t = 1; t < 8; ++t) sv = (lane == t) ? wi[t] : sv;
      if (lane < 8) swin[lane] = sv;
      if (lane == 0) s_p = p;
    }
    __syncthreads();   // B

    // ---- all threads: read winners, apply p commits in order ----
    const int p = s_p;
    int wiu[8], rows8[8], cls8[8];
#pragma unroll
    for (int t = 0; t < 8; ++t) {
      int w = swin[t];
      wiu[t] = __builtin_amdgcn_readfirstlane(w);     // force SGPR (uniform)
      int idx = (wiu[t] < 0) ? 0 : wiu[t];
      rows8[t] = idx / NC; cls8[t] = idx - rows8[t] * NC;
    }
    float4 cb[8], ob[8];
#pragma unroll
    for (int t = 0; t < 8; ++t) if (t < p) {
      cb[t] = *(const float4*)(boxes + (size_t)wiu[t] * 4);            // s_load (uniform)
      ob[t] = *(const float4*)(boxes + ((size_t)j * NC + cls8[t]) * 4);
    }
#pragma unroll
    for (int t = 0; t < 8; ++t) if (t < p) {
      if (j == rows8[t]) {
        // commit: col update overwritten by row := -1 (reference order)
        retired = true; commitcls = cls8[t]; post_min = INT_MAX;
      } else if (overlap_ge(cb[t], ob[t])) {
        if (retired) {
          post_min = (cls8[t] < post_min) ? cls8[t] : post_min;  // resurrect -1 -> 0.0
        } else {
          int c = cls8[t];
#pragma unroll
          for (int k5 = 0; k5 < 5; ++k5) if (k5 == (c >> 5)) mask[k5] |= (1u << (c & 31));
        }
      }
    }

    // ---- recompute my candidate ----
    if (retired) {
      rowmax = (post_min != INT_MAX) ? 0.0f : -1.0f;
      argcls = (post_min != INT_MAX) ? post_min : 0;
    } else if (!zstuck) {
      bool found = false;
#pragma unroll
      for (int t = 0; t < 8; ++t) {
        if (!found && lv[t] > 0.f && !mbit(mask, lc[t])) {
          rowmax = lv[t]; argcls = lc[t]; found = true;
        }
      }
      if (!found) {
        // rare: full rescan with LIST REFILL (exact same prob recompute as phase A)
        float bm = -3.4e38f; int ba = 0;
#pragma unroll
        for (int t = 0; t < 8; ++t) { lv[t] = -3.4e38f; lc[t] = 0; }
        if (USEWS) {
          for (int c4 = 0; c4 < PST / 4; ++c4) {
            float4 v4 = *(const float4*)(xr + c4 * 4);
            int c = c4 * 4;
            float vals[4] = {v4.x, v4.y, v4.z, v4.w};
#pragma unroll
            for (int u = 0; u < 4; ++u) {
              int cc = c + u;
              float v = (cc == 0) ? 0.f
                       : (mbit(mask, cc) ? 0.f : expf(vals[u] - m_) / s_);  // pad -> 0
              if (v > bm) { bm = v; ba = cc; }   // cc=0 hits first; pad(0) never replaces
              if (v > 0.f) ins(v, cc);
            }
          }
        } else {
          for (int c = 0; c < NC; ++c) {
            float v;
            if (c == 0) v = 0.f;
            else v = mbit(mask, c) ? 0.f : (expf(xr[c] - m_) / s_);
            if (v > bm) { bm = v; ba = c; }
            if (v > 0.f) ins(v, c);
          }
        }
        rowmax = bm; argcls = ba;
        if (!(bm > 0.f)) zstuck = true;   // all-zero row: candidate stable forever
      }
    }
    // zstuck: keep (rowmax, argcls) — values never increase for this row

    committed += p;
  }

  commits[j] = (float)commitcls;
}

extern "C" void kernel_launch(void* const* d_in, const int* in_sizes, int n_in,
                              void* d_out, int out_size, void* d_ws, size_t ws_size,
                              hipStream_t stream) {
  const float* A     = (const float*)d_in[0];   // obj_fmap [512,4096]
  const float* boxes = (const float*)d_in[1];   // boxes_per_cls [512,151,4]
  const float* W     = (const float*)d_in[2];   // [4096,151]
  const float* bias  = (const float*)d_in[3];   // [151]
  float* out = (float*)d_out;                   // [512*151] obj_dists ++ [512] commits

  const size_t need = (size_t)(KS * NB + NB) * PST * 4;
  if (ws_size >= need) {
    float* part = (float*)d_ws;
    float* lp   = part + (size_t)KS * NB * PST;
    gemm_partial<<<dim3(NB / GRB, KS), 192, 0, stream>>>(A, W, part);
    gemm_reduce<<<(NB * PST + 255) / 256, 256, 0, stream>>>(part, bias, out, lp);
    decode_kernel<true><<<1, NB, 0, stream>>>(lp, boxes, out + NB * NC);
  } else {
    gemm_full<<<NB / 4, 192, 0, stream>>>(A, W, bias, out);
    decode_kernel<false><<<1, NB, 0, stream>>>(out, boxes, out + NB * NC);
  }
}

// Round 7
// 549.133 us; speedup vs baseline: 1.4907x; 1.1225x over previous
//
#include <hip/hip_runtime.h>
#include <limits.h>

#pragma clang fp contract(off)

#define NB 512
#define NC 151
#define KDIM 4096
#define KS 8
#define KCH (KDIM/KS)      // 512
#define GRB 16             // gemm rows per block
#define PST 152            // padded row stride (floats), 16B-aligned rows
#define NMS_TH 0.3f

typedef unsigned long long ull;

// ---------------- DPP wave64 reductions ----------------
template <int CTRL>
__device__ __forceinline__ int dpp_i(int identity, int x) {
  return __builtin_amdgcn_update_dpp(identity, x, CTRL, 0xF, 0xF, false);
}
__device__ __forceinline__ float wave_max_bcast(float x) {
  const int ID = __float_as_int(-3.4e38f);
  x = fmaxf(x, __int_as_float(dpp_i<0x111>(ID, __float_as_int(x))));  // row_shr:1
  x = fmaxf(x, __int_as_float(dpp_i<0x112>(ID, __float_as_int(x))));  // row_shr:2
  x = fmaxf(x, __int_as_float(dpp_i<0x114>(ID, __float_as_int(x))));  // row_shr:4
  x = fmaxf(x, __int_as_float(dpp_i<0x118>(ID, __float_as_int(x))));  // row_shr:8
  x = fmaxf(x, __int_as_float(dpp_i<0x142>(ID, __float_as_int(x))));  // row_bcast:15
  x = fmaxf(x, __int_as_float(dpp_i<0x143>(ID, __float_as_int(x))));  // row_bcast:31
  return __int_as_float(__builtin_amdgcn_readlane(__float_as_int(x), 63));
}
__device__ __forceinline__ int wave_min_bcast_i(int x) {
  int y;
  y = dpp_i<0x111>(INT_MAX, x); x = (x < y) ? x : y;
  y = dpp_i<0x112>(INT_MAX, x); x = (x < y) ? x : y;
  y = dpp_i<0x114>(INT_MAX, x); x = (x < y) ? x : y;
  y = dpp_i<0x118>(INT_MAX, x); x = (x < y) ? x : y;
  y = dpp_i<0x142>(INT_MAX, x); x = (x < y) ? x : y;
  y = dpp_i<0x143>(INT_MAX, x); x = (x < y) ? x : y;
  return __builtin_amdgcn_readlane(x, 63);
}

// exact reference IoU arithmetic (fp contract off file-wide)
__device__ __forceinline__ bool overlap_ge(const float4& c, const float4& o) {
  float areaC = (c.z - c.x + 1.0f) * (c.w - c.y + 1.0f);
  float areaJ = (o.z - o.x + 1.0f) * (o.w - o.y + 1.0f);
  float iw = fminf(c.z, o.z) - fmaxf(c.x, o.x) + 1.0f;
  float ih = fminf(c.w, o.w) - fmaxf(c.y, o.y) + 1.0f;
  iw = fmaxf(iw, 0.0f); ih = fmaxf(ih, 0.0f);
  float inter = iw * ih;
  float uni = areaC + areaJ - inter;
  return inter / uni >= NMS_TH;
}

__device__ __forceinline__ bool mbit(const unsigned m[5], int c) {
  bool r = false;
#pragma unroll
  for (int k = 0; k < 5; ++k) r = (k == (c >> 5)) ? (((m[k] >> (c & 31)) & 1u) != 0) : r;
  return r;
}

// ---------------- boxes transpose: [NB][NC][4] -> bt [NC][NB][4] ----------------
__global__ void transpose_boxes(const float* __restrict__ boxes, float* __restrict__ bt) {
  int i = blockIdx.x * 256 + threadIdx.x;
  if (i >= NB * NC) return;
  int r = i / NC, c = i - r * NC;
  float4 v = *(const float4*)(boxes + (size_t)i * 4);        // coalesced read
  *(float4*)(bt + ((size_t)c * NB + r) * 4) = v;             // scattered write (once)
}

// ---------------- GEMM split-K partials (LDS staging + W prefetch) ----------------
__global__ __launch_bounds__(192) void gemm_partial(
    const float* __restrict__ A, const float* __restrict__ W, float* __restrict__ part)
{
  __shared__ float sA[GRB * KCH];  // 32 KB
  int rb = blockIdx.x, ks = blockIdx.y;
  const float* Ab = A + (size_t)rb * GRB * KDIM + (size_t)ks * KCH;
  for (int i = threadIdx.x; i < GRB * (KCH / 4); i += 192) {
    int r = i >> 7;            // KCH/4 = 128
    int k4 = i & 127;
    *(float4*)(sA + r * KCH + k4 * 4) = *(const float4*)(Ab + (size_t)r * KDIM + k4 * 4);
  }
  __syncthreads();
  int c = threadIdx.x;
  if (c < NC) {
    const float* wp = W + (size_t)ks * KCH * NC + c;
    float acc[GRB];
#pragma unroll
    for (int r = 0; r < GRB; ++r) acc[r] = 0.f;
    float w0 = wp[0], w1 = wp[NC], w2 = wp[2 * NC], w3 = wp[3 * NC];
    for (int k4 = 0; k4 < KCH / 4; ++k4) {
      int kn = (k4 + 1 < KCH / 4) ? (k4 + 1) : k4;     // clamp: re-read last (no OOB)
      const float* q = wp + (size_t)(4 * kn) * NC;
      float n0 = q[0], n1 = q[NC], n2 = q[2 * NC], n3 = q[3 * NC];
#pragma unroll
      for (int r = 0; r < GRB; ++r) {
        float4 a = *(const float4*)(sA + r * KCH + k4 * 4);  // broadcast read
        acc[r] = fmaf(a.x, w0, acc[r]);
        acc[r] = fmaf(a.y, w1, acc[r]);
        acc[r] = fmaf(a.z, w2, acc[r]);
        acc[r] = fmaf(a.w, w3, acc[r]);
      }
      w0 = n0; w1 = n1; w2 = n2; w3 = n3;
    }
    float* o = part + ((size_t)ks * NB + (size_t)rb * GRB) * PST + c;
#pragma unroll
    for (int r = 0; r < GRB; ++r) o[(size_t)r * PST] = acc[r];
  }
}

// finish: obj_dists -> out, padded logits (-inf pad) -> lp (ws)
__global__ void gemm_reduce(const float* __restrict__ part, const float* __restrict__ bias,
                            float* __restrict__ out, float* __restrict__ lp) {
  int i = blockIdx.x * 256 + threadIdx.x;
  if (i >= NB * PST) return;
  int r = i / PST, c = i - r * PST;
  float acc = 0.f;
#pragma unroll
  for (int ks = 0; ks < KS; ++ks) acc += part[((size_t)ks * NB + r) * PST + c];
  float val;
  if (c < NC) { val = acc + bias[c]; out[(size_t)r * NC + c] = val; }
  else val = -3.4e38f;
  lp[i] = val;
}

// ---------------- parallel softmax + per-row top-8 list build ----------------
// lp: logits in (pad -inf) -> probs out (class0=0, pad=0). tl: [NB][16] floats:
// [0..7]=lv desc, [8..15]=bitcast lc. Exactly the decode phase-A math/order.
__global__ __launch_bounds__(64) void softmax_prep(
    float* __restrict__ lp, float* __restrict__ tl)
{
  int j = blockIdx.x * 64 + threadIdx.x;
  if (j >= NB) return;
  float* xr = lp + (size_t)j * PST;

  float lv[8]; int lc[8];
#pragma unroll
  for (int t = 0; t < 8; ++t) { lv[t] = -3.4e38f; lc[t] = 0; }

  float m_ = -3.4e38f, s_ = 0.f;
  for (int c4 = 0; c4 < PST / 4; ++c4) {
    float4 v = *(const float4*)(xr + c4 * 4);
    m_ = fmaxf(fmaxf(fmaxf(m_, v.x), fmaxf(v.y, v.z)), v.w);   // pad=-inf never wins
  }
  for (int c4 = 0; c4 < PST / 4; ++c4) {
    float4 v = *(const float4*)(xr + c4 * 4);
    s_ += expf(v.x - m_); s_ += expf(v.y - m_);
    s_ += expf(v.z - m_); s_ += expf(v.w - m_);                // pad: exp(-inf)=0
  }
  for (int c4 = 0; c4 < PST / 4; ++c4) {
    float4 v = *(const float4*)(xr + c4 * 4);
    int c = c4 * 4;
    float p0 = (c == 0) ? 0.f : expf(v.x - m_) / s_;
    float p1 = expf(v.y - m_) / s_;
    float p2 = expf(v.z - m_) / s_;
    float p3 = expf(v.w - m_) / s_;
    float4 st; st.x = p0; st.y = p1; st.z = p2; st.w = p3;     // pad -> 0
    *(float4*)(xr + c4 * 4) = st;
    // stable-desc insert (first occurrence wins ties)
#pragma unroll
    for (int u = 0; u < 4; ++u) {
      float pv = (u == 0) ? p0 : (u == 1) ? p1 : (u == 2) ? p2 : p3;
      int cc = c + u;
      if (pv > 0.f && pv > lv[7]) {
        lv[7] = pv; lc[7] = cc;
#pragma unroll
        for (int q = 7; q > 0; --q) {
          if (lv[q] > lv[q - 1]) {
            float tv = lv[q]; lv[q] = lv[q - 1]; lv[q - 1] = tv;
            int tc = lc[q]; lc[q] = lc[q - 1]; lc[q - 1] = tc;
          }
        }
      }
    }
  }
  float* tr = tl + (size_t)j * 16;
#pragma unroll
  for (int t = 0; t < 8; ++t) { tr[t] = lv[t]; tr[8 + t] = __int_as_float(lc[t]); }
}

// fallback gemm (ws too small)
__global__ __launch_bounds__(192) void gemm_full(
    const float* __restrict__ A, const float* __restrict__ W,
    const float* __restrict__ bias, float* __restrict__ out)
{
  int c = threadIdx.x;
  int r0 = blockIdx.x * 4;
  if (c >= NC) return;
  const float* a = A + (size_t)r0 * KDIM;
  const float* wp = W + c;
  float a0 = 0.f, a1 = 0.f, a2 = 0.f, a3 = 0.f;
#pragma unroll 8
  for (int k = 0; k < KDIM; ++k) {
    float w = wp[(size_t)k * NC];
    a0 = fmaf(a[k],            w, a0);
    a1 = fmaf(a[k + KDIM],     w, a1);
    a2 = fmaf(a[k + 2 * KDIM], w, a2);
    a3 = fmaf(a[k + 3 * KDIM], w, a3);
  }
  float bb = bias[c];
  out[(size_t)(r0 + 0) * NC + c] = a0 + bb;
  out[(size_t)(r0 + 1) * NC + c] = a1 + bb;
  out[(size_t)(r0 + 2) * NC + c] = a2 + bb;
  out[(size_t)(r0 + 3) * NC + c] = a3 + bb;
}

// ---------------- Multi-commit greedy NMS decode ----------------
// FAST: probs in lp [NB][PST], top-8 lists in tl, boxes transposed bt [NC][NB][4]
//       (apply loads are lane-contiguous). Else: round-6 fallback layout.
template <bool FAST>
__global__ __launch_bounds__(512) void decode_kernel(
    const float* __restrict__ lp, const float* __restrict__ tl,
    const float* __restrict__ boxes /* FAST: bt ; else raw boxes */,
    float* __restrict__ commits)
{
  __shared__ ull cand[NB];    // 4 KB
  __shared__ int swin[8];
  __shared__ int s_p;
  const int j = threadIdx.x;
  const int lane = j & 63;

  float lv[8]; int lc[8];
  float m_ = 0.f, s_ = 1.f;
  const float* xr = FAST ? (lp + (size_t)j * PST) : (lp + (size_t)j * NC);

  if (FAST) {
    const float4* tl4 = (const float4*)(tl + (size_t)j * 16);
    float4 a0 = tl4[0], a1 = tl4[1], b0 = tl4[2], b1 = tl4[3];
    lv[0] = a0.x; lv[1] = a0.y; lv[2] = a0.z; lv[3] = a0.w;
    lv[4] = a1.x; lv[5] = a1.y; lv[6] = a1.z; lv[7] = a1.w;
    lc[0] = __float_as_int(b0.x); lc[1] = __float_as_int(b0.y);
    lc[2] = __float_as_int(b0.z); lc[3] = __float_as_int(b0.w);
    lc[4] = __float_as_int(b1.x); lc[5] = __float_as_int(b1.y);
    lc[6] = __float_as_int(b1.z); lc[7] = __float_as_int(b1.w);
  } else {
#pragma unroll
    for (int t = 0; t < 8; ++t) { lv[t] = -3.4e38f; lc[t] = 0; }
    m_ = xr[0];
    for (int c = 1; c < NC; ++c) m_ = fmaxf(m_, xr[c]);
    s_ = 0.f;
    for (int c = 0; c < NC; ++c) s_ += expf(xr[c] - m_);
    for (int c = 1; c < NC; ++c) {
      float v = expf(xr[c] - m_) / s_;
      if (v > lv[7]) {
        lv[7] = v; lc[7] = c;
#pragma unroll
        for (int q = 7; q > 0; --q) {
          if (lv[q] > lv[q - 1]) {
            float tv = lv[q]; lv[q] = lv[q - 1]; lv[q - 1] = tv;
            int tc = lc[q]; lc[q] = lc[q - 1]; lc[q - 1] = tc;
          }
        }
      }
    }
  }

  float rowmax; int argcls; bool zstuck = false;
  if (lv[0] > 0.f) { rowmax = lv[0]; argcls = lc[0]; }
  else { rowmax = 0.f; argcls = 0; zstuck = true; }

  unsigned mask[5] = {0, 0, 0, 0, 0};
  bool retired = false;
  int post_min = INT_MAX;
  int commitcls = 0;
  int committed = 0;

  while (committed < NB) {
    cand[j] = ((ull)(unsigned)__float_as_int(rowmax) << 32) | (unsigned)(j * NC + argcls);
    __syncthreads();   // A

    if (j < 64) {
      // ---- wave 0 only: gather + exact top-8 extraction + validity + prefix ----
      float vv[8]; int vi[8];
#pragma unroll
      for (int t = 0; t < 8; ++t) {
        ull k = cand[lane + 64 * t];
        vv[t] = __int_as_float((int)(k >> 32));
        vi[t] = (int)(unsigned)(k & 0xFFFFFFFFu);
      }
      float lmv = vv[0]; int lmi = vi[0];
#pragma unroll
      for (int t = 1; t < 8; ++t) if (vv[t] > lmv) { lmv = vv[t]; lmi = vi[t]; }

      int wi[8]; unsigned okm = 0;
      int kmax = NB - committed; if (kmax > 8) kmax = 8;
      bool stop = false;
#pragma unroll
      for (int t = 0; t < 8; ++t) {
        if (t >= kmax || stop) { wi[t] = -1; continue; }
        float gv = wave_max_bcast(lmv);
        ull tied = __ballot(lmv == gv);
        int gi;
        if (__popcll(tied) == 1) {
          gi = __builtin_amdgcn_readlane(lmi, (int)__ffsll(tied) - 1);
        } else {
          gi = wave_min_bcast_i((lmv == gv) ? lmi : INT_MAX);  // exact min-flat-idx tie-break
        }
        wi[t] = gi;
        if (gv > 0.f) okm |= (1u << t); else stop = true;
        if (lmi == gi) {   // winner lane pops and rescans its 8
#pragma unroll
          for (int u = 0; u < 8; ++u) if (vi[u] == gi) vv[u] = -3.0e38f;
          lmv = vv[0]; lmi = vi[0];
#pragma unroll
          for (int u = 1; u < 8; ++u) if (vv[u] > lmv) { lmv = vv[u]; lmi = vi[u]; }
        }
      }

      int cls8[8];
#pragma unroll
      for (int t = 0; t < 8; ++t) {
        int idx = (wi[t] < 0) ? 0 : wi[t];
        cls8[t] = idx - (idx / NC) * NC;
      }

      // pairwise validity: lane (t,s) = (lane>>3, lane&7), s<t
      int lt = lane >> 3, ls = lane & 7;
      int iT = wi[0], iS = wi[0], cT = cls8[0], cS = cls8[0];
#pragma unroll
      for (int t = 1; t < 8; ++t) {
        iT = (lt == t) ? wi[t]   : iT;  cT = (lt == t) ? cls8[t] : cT;
        iS = (ls == t) ? wi[t]   : iS;  cS = (ls == t) ? cls8[t] : cS;
      }
      bool sup = false;
      if (ls < lt && ((okm >> lt) & 1) && ((okm >> ls) & 1) && cT == cS && iT >= 0 && iS >= 0) {
        float4 bs, btx;
        if (FAST) {
          int rS = iS / NC, rT = iT / NC;
          bs  = *(const float4*)(boxes + ((size_t)cS * NB + rS) * 4);
          btx = *(const float4*)(boxes + ((size_t)cT * NB + rT) * 4);
        } else {
          bs  = *(const float4*)(boxes + (size_t)iS * 4);
          btx = *(const float4*)(boxes + (size_t)iT * 4);
        }
        sup = overlap_ge(bs, btx);
      }
      ull B = __ballot(sup);   // bit (8*t + s)
      unsigned validset = 1; int p = 1;
#pragma unroll
      for (int t = 1; t < 8; ++t) {
        if (p == t && ((okm >> t) & 1) && (((B >> (8 * t)) & (ull)validset) == 0)) {
          validset |= (1u << t); p = t + 1;
        }
      }

      int sv = wi[0];
#pragma unroll
      for (int t = 1; t < 8; ++t) sv = (lane == t) ? wi[t] : sv;
      if (lane < 8) swin[lane] = sv;
      if (lane == 0) s_p = p;
    }
    __syncthreads();   // B

    // ---- all threads: read winners, apply p commits in order ----
    const int p = s_p;
    int wiu[8], rows8[8], cls8[8];
#pragma unroll
    for (int t = 0; t < 8; ++t) {
      int w = swin[t];
      wiu[t] = __builtin_amdgcn_readfirstlane(w);     // force SGPR (uniform)
      int idx = (wiu[t] < 0) ? 0 : wiu[t];
      rows8[t] = idx / NC; cls8[t] = idx - rows8[t] * NC;
    }
    float4 cb[8], ob[8];
#pragma unroll
    for (int t = 0; t < 8; ++t) if (t < p) {
      if (FAST) {
        const float* btc = boxes + (size_t)cls8[t] * NB * 4;
        cb[t] = *(const float4*)(btc + (size_t)rows8[t] * 4);   // uniform -> s_load
        ob[t] = *(const float4*)(btc + (size_t)j * 4);          // lane-contiguous, dense
      } else {
        cb[t] = *(const float4*)(boxes + (size_t)wiu[t] * 4);
        ob[t] = *(const float4*)(boxes + ((size_t)j * NC + cls8[t]) * 4);
      }
    }
#pragma unroll
    for (int t = 0; t < 8; ++t) if (t < p) {
      if (j == rows8[t]) {
        // commit: col update overwritten by row := -1 (reference order)
        retired = true; commitcls = cls8[t]; post_min = INT_MAX;
      } else if (overlap_ge(cb[t], ob[t])) {
        if (retired) {
          post_min = (cls8[t] < post_min) ? cls8[t] : post_min;  // resurrect -1 -> 0.0
        } else {
          int c = cls8[t];
#pragma unroll
          for (int k5 = 0; k5 < 5; ++k5) if (k5 == (c >> 5)) mask[k5] |= (1u << (c & 31));
        }
      }
    }

    // ---- recompute my candidate ----
    if (retired) {
      rowmax = (post_min != INT_MAX) ? 0.0f : -1.0f;
      argcls = (post_min != INT_MAX) ? post_min : 0;
    } else if (!zstuck) {
      bool found = false;
#pragma unroll
      for (int t = 0; t < 8; ++t) {
        if (!found && lv[t] > 0.f && !mbit(mask, lc[t])) {
          rowmax = lv[t]; argcls = lc[t]; found = true;
        }
      }
      if (!found) {
        // rare: full rescan with list refill. FAST: stored probs, no transcendentals.
        float bm = -3.4e38f; int ba = 0;
#pragma unroll
        for (int t = 0; t < 8; ++t) { lv[t] = -3.4e38f; lc[t] = 0; }
        auto ins = [&](float v, int c) {
          if (v > lv[7]) {
            lv[7] = v; lc[7] = c;
#pragma unroll
            for (int q = 7; q > 0; --q) {
              if (lv[q] > lv[q - 1]) {
                float tv = lv[q]; lv[q] = lv[q - 1]; lv[q - 1] = tv;
                int tc = lc[q]; lc[q] = lc[q - 1]; lc[q - 1] = tc;
              }
            }
          }
        };
        if (FAST) {
          for (int c4 = 0; c4 < PST / 4; ++c4) {
            float4 v4 = *(const float4*)(xr + c4 * 4);   // probs; class0=0, pad=0
            int c = c4 * 4;
            float vals[4] = {v4.x, v4.y, v4.z, v4.w};
#pragma unroll
            for (int u = 0; u < 4; ++u) {
              int cc = c + u;
              float v = mbit(mask, cc) ? 0.f : vals[u];
              if (v > bm) { bm = v; ba = cc; }   // cc=0 (v=0) hits first; pads never exceed
              if (v > 0.f) ins(v, cc);
            }
          }
        } else {
          for (int c = 0; c < NC; ++c) {
            float v;
            if (c == 0) v = 0.f;
            else v = mbit(mask, c) ? 0.f : (expf(xr[c] - m_) / s_);
            if (v > bm) { bm = v; ba = c; }
            if (v > 0.f) ins(v, c);
          }
        }
        rowmax = bm; argcls = ba;
        if (!(bm > 0.f)) zstuck = true;   // all-zero row: candidate stable forever
      }
    }
    // zstuck: keep (rowmax, argcls) — values never increase for this row

    committed += p;
  }

  commits[j] = (float)commitcls;
}

extern "C" void kernel_launch(void* const* d_in, const int* in_sizes, int n_in,
                              void* d_out, int out_size, void* d_ws, size_t ws_size,
                              hipStream_t stream) {
  const float* A     = (const float*)d_in[0];   // obj_fmap [512,4096]
  const float* boxes = (const float*)d_in[1];   // boxes_per_cls [512,151,4]
  const float* W     = (const float*)d_in[2];   // [4096,151]
  const float* bias  = (const float*)d_in[3];   // [151]
  float* out = (float*)d_out;                   // [512*151] obj_dists ++ [512] commits

  const size_t np = (size_t)KS * NB * PST;      // part
  const size_t nl = (size_t)NB * PST;           // lp
  const size_t nt = (size_t)NB * 16;            // tl
  const size_t nb = (size_t)NC * NB * 4;        // bt
  const size_t need = (np + nl + nt + nb) * 4;

  if (ws_size >= need) {
    float* part = (float*)d_ws;
    float* lp   = part + np;
    float* tl   = lp + nl;
    float* bt   = tl + nt;
    transpose_boxes<<<(NB * NC + 255) / 256, 256, 0, stream>>>(boxes, bt);
    gemm_partial<<<dim3(NB / GRB, KS), 192, 0, stream>>>(A, W, part);
    gemm_reduce<<<(NB * PST + 255) / 256, 256, 0, stream>>>(part, bias, out, lp);
    softmax_prep<<<NB / 64, 64, 0, stream>>>(lp, tl);
    decode_kernel<true><<<1, NB, 0, stream>>>(lp, tl, bt, out + NB * NC);
  } else {
    gemm_full<<<NB / 4, 192, 0, stream>>>(A, W, bias, out);
    decode_kernel<false><<<1, NB, 0, stream>>>(out, nullptr, boxes, out + NB * NC);
  }
}

// Round 8
// 546.000 us; speedup vs baseline: 1.4992x; 1.0057x over previous
//
#include <hip/hip_runtime.h>
#include <limits.h>

#pragma clang fp contract(off)

#define NB 512
#define NC 151
#define KDIM 4096
#define KS 8
#define KCH (KDIM/KS)      // 512
#define GRB 16             // gemm rows per block
#define PST 152            // padded row stride (floats), 16B-aligned rows
#define NK 16              // commits per round
#define NMS_TH 0.3f

typedef unsigned long long ull;

// ---------------- DPP wave64 reductions ----------------
template <int CTRL>
__device__ __forceinline__ int dpp_i(int identity, int x) {
  return __builtin_amdgcn_update_dpp(identity, x, CTRL, 0xF, 0xF, false);
}
__device__ __forceinline__ float wave_max_bcast(float x) {
  const int ID = __float_as_int(-3.4e38f);
  x = fmaxf(x, __int_as_float(dpp_i<0x111>(ID, __float_as_int(x))));  // row_shr:1
  x = fmaxf(x, __int_as_float(dpp_i<0x112>(ID, __float_as_int(x))));  // row_shr:2
  x = fmaxf(x, __int_as_float(dpp_i<0x114>(ID, __float_as_int(x))));  // row_shr:4
  x = fmaxf(x, __int_as_float(dpp_i<0x118>(ID, __float_as_int(x))));  // row_shr:8
  x = fmaxf(x, __int_as_float(dpp_i<0x142>(ID, __float_as_int(x))));  // row_bcast:15
  x = fmaxf(x, __int_as_float(dpp_i<0x143>(ID, __float_as_int(x))));  // row_bcast:31
  return __int_as_float(__builtin_amdgcn_readlane(__float_as_int(x), 63));
}
__device__ __forceinline__ int wave_min_bcast_i(int x) {
  int y;
  y = dpp_i<0x111>(INT_MAX, x); x = (x < y) ? x : y;
  y = dpp_i<0x112>(INT_MAX, x); x = (x < y) ? x : y;
  y = dpp_i<0x114>(INT_MAX, x); x = (x < y) ? x : y;
  y = dpp_i<0x118>(INT_MAX, x); x = (x < y) ? x : y;
  y = dpp_i<0x142>(INT_MAX, x); x = (x < y) ? x : y;
  y = dpp_i<0x143>(INT_MAX, x); x = (x < y) ? x : y;
  return __builtin_amdgcn_readlane(x, 63);
}

// exact reference IoU arithmetic (fp contract off file-wide)
__device__ __forceinline__ bool overlap_ge(const float4& c, const float4& o) {
  float areaC = (c.z - c.x + 1.0f) * (c.w - c.y + 1.0f);
  float areaJ = (o.z - o.x + 1.0f) * (o.w - o.y + 1.0f);
  float iw = fminf(c.z, o.z) - fmaxf(c.x, o.x) + 1.0f;
  float ih = fminf(c.w, o.w) - fmaxf(c.y, o.y) + 1.0f;
  iw = fmaxf(iw, 0.0f); ih = fmaxf(ih, 0.0f);
  float inter = iw * ih;
  float uni = areaC + areaJ - inter;
  return inter / uni >= NMS_TH;
}

__device__ __forceinline__ bool mbit(const unsigned m[5], int c) {
  bool r = false;
#pragma unroll
  for (int k = 0; k < 5; ++k) r = (k == (c >> 5)) ? (((m[k] >> (c & 31)) & 1u) != 0) : r;
  return r;
}

// ---------------- kernel 1: fused GEMM split-K partials + boxes transpose ----------------
// blocks [0,256): gemm (rb = bx>>3, ks = bx&7); blocks [256,659): transpose chunk.
#define TPB_GEMM 256
#define NTR ((NB * NC + 191) / 192)   // 403
__global__ __launch_bounds__(192) void gemm_fused(
    const float* __restrict__ A, const float* __restrict__ W,
    const float* __restrict__ boxes, float* __restrict__ part, float* __restrict__ bt)
{
  if (blockIdx.x >= TPB_GEMM) {
    int i = (blockIdx.x - TPB_GEMM) * 192 + threadIdx.x;
    if (i < NB * NC) {
      int r = i / NC, c = i - r * NC;
      float4 v = *(const float4*)(boxes + (size_t)i * 4);      // coalesced read
      *(float4*)(bt + ((size_t)c * NB + r) * 4) = v;           // scattered write (once)
    }
    return;
  }
  __shared__ float sA[GRB * KCH];  // 32 KB
  int rb = blockIdx.x >> 3, ks = blockIdx.x & 7;
  const float* Ab = A + (size_t)rb * GRB * KDIM + (size_t)ks * KCH;
  for (int i = threadIdx.x; i < GRB * (KCH / 4); i += 192) {
    int r = i >> 7;            // KCH/4 = 128
    int k4 = i & 127;
    *(float4*)(sA + r * KCH + k4 * 4) = *(const float4*)(Ab + (size_t)r * KDIM + k4 * 4);
  }
  __syncthreads();
  int c = threadIdx.x;
  if (c < NC) {
    const float* wp = W + (size_t)ks * KCH * NC + c;
    float acc[GRB];
#pragma unroll
    for (int r = 0; r < GRB; ++r) acc[r] = 0.f;
    float w0 = wp[0], w1 = wp[NC], w2 = wp[2 * NC], w3 = wp[3 * NC];
    for (int k4 = 0; k4 < KCH / 4; ++k4) {
      int kn = (k4 + 1 < KCH / 4) ? (k4 + 1) : k4;     // clamp: re-read last (no OOB)
      const float* q = wp + (size_t)(4 * kn) * NC;
      float n0 = q[0], n1 = q[NC], n2 = q[2 * NC], n3 = q[3 * NC];
#pragma unroll
      for (int r = 0; r < GRB; ++r) {
        float4 a = *(const float4*)(sA + r * KCH + k4 * 4);  // broadcast read
        acc[r] = fmaf(a.x, w0, acc[r]);
        acc[r] = fmaf(a.y, w1, acc[r]);
        acc[r] = fmaf(a.z, w2, acc[r]);
        acc[r] = fmaf(a.w, w3, acc[r]);
      }
      w0 = n0; w1 = n1; w2 = n2; w3 = n3;
    }
    float* o = part + ((size_t)ks * NB + (size_t)rb * GRB) * PST + c;
#pragma unroll
    for (int r = 0; r < GRB; ++r) o[(size_t)r * PST] = acc[r];
  }
}

// ---------------- kernel 2: reduce + obj_dists + softmax probs + top-8 list ----------------
// one thread per row. lp gets probs (class0=0, pad=0); tl[j][0..7]=lv, [8..15]=bitcast lc.
__global__ __launch_bounds__(64) void prep_kernel(
    const float* __restrict__ part, const float* __restrict__ bias,
    float* __restrict__ out, float* __restrict__ lp, float* __restrict__ tl)
{
  int j = blockIdx.x * 64 + threadIdx.x;
  if (j >= NB) return;
  float* pr = lp + (size_t)j * PST;
  float* orow = out + (size_t)j * NC;

  float m_ = -3.4e38f;
  // pass1: sum split-K partials + bias -> logits into pr and out; track max
  for (int c4 = 0; c4 < PST / 4; ++c4) {
    float x0 = 0.f, x1 = 0.f, x2 = 0.f, x3 = 0.f;
#pragma unroll
    for (int ks = 0; ks < KS; ++ks) {
      const float4 v = *(const float4*)(part + ((size_t)ks * NB + j) * PST + c4 * 4);
      x0 += v.x; x1 += v.y; x2 += v.z; x3 += v.w;
    }
    int c = c4 * 4;
    x0 += bias[c];
    if (c + 1 < NC) x1 += bias[c + 1];
    if (c + 2 < NC) x2 += bias[c + 2];
    if (c + 3 < NC) x3 += bias[c + 3];
    float4 st; st.x = x0; st.y = (c + 1 < NC) ? x1 : -3.4e38f;
    st.z = (c + 2 < NC) ? x2 : -3.4e38f; st.w = (c + 3 < NC) ? x3 : -3.4e38f;
    *(float4*)(pr + c4 * 4) = st;
    orow[c] = x0;
    if (c + 1 < NC) orow[c + 1] = x1;
    if (c + 2 < NC) orow[c + 2] = x2;
    if (c + 3 < NC) orow[c + 3] = x3;
    m_ = fmaxf(m_, st.x); m_ = fmaxf(m_, st.y);
    m_ = fmaxf(m_, st.z); m_ = fmaxf(m_, st.w);
  }
  // pass2: s accumulation (ascending, same order as before)
  float s_ = 0.f;
  for (int c4 = 0; c4 < PST / 4; ++c4) {
    float4 v = *(const float4*)(pr + c4 * 4);
    s_ += expf(v.x - m_); s_ += expf(v.y - m_);
    s_ += expf(v.z - m_); s_ += expf(v.w - m_);    // pad: exp(-inf-ish)=0
  }
  // pass3: probs + top-8 (stable desc)
  float lv[8]; int lc[8];
#pragma unroll
  for (int t = 0; t < 8; ++t) { lv[t] = -3.4e38f; lc[t] = 0; }
  for (int c4 = 0; c4 < PST / 4; ++c4) {
    float4 v = *(const float4*)(pr + c4 * 4);
    int c = c4 * 4;
    float p0 = (c == 0) ? 0.f : expf(v.x - m_) / s_;
    float p1 = expf(v.y - m_) / s_;
    float p2 = expf(v.z - m_) / s_;
    float p3 = expf(v.w - m_) / s_;
    float4 st; st.x = p0; st.y = p1; st.z = p2; st.w = p3;   // pad -> 0
    *(float4*)(pr + c4 * 4) = st;
#pragma unroll
    for (int u = 0; u < 4; ++u) {
      float pv = (u == 0) ? p0 : (u == 1) ? p1 : (u == 2) ? p2 : p3;
      int cc = c + u;
      if (pv > 0.f && pv > lv[7]) {
        lv[7] = pv; lc[7] = cc;
#pragma unroll
        for (int q = 7; q > 0; --q) {
          if (lv[q] > lv[q - 1]) {
            float tv = lv[q]; lv[q] = lv[q - 1]; lv[q - 1] = tv;
            int tc = lc[q]; lc[q] = lc[q - 1]; lc[q - 1] = tc;
          }
        }
      }
    }
  }
  float* tr = tl + (size_t)j * 16;
#pragma unroll
  for (int t = 0; t < 8; ++t) { tr[t] = lv[t]; tr[8 + t] = __int_as_float(lc[t]); }
}

// fallback gemm (ws too small)
__global__ __launch_bounds__(192) void gemm_full(
    const float* __restrict__ A, const float* __restrict__ W,
    const float* __restrict__ bias, float* __restrict__ out)
{
  int c = threadIdx.x;
  int r0 = blockIdx.x * 4;
  if (c >= NC) return;
  const float* a = A + (size_t)r0 * KDIM;
  const float* wp = W + c;
  float a0 = 0.f, a1 = 0.f, a2 = 0.f, a3 = 0.f;
#pragma unroll 8
  for (int k = 0; k < KDIM; ++k) {
    float w = wp[(size_t)k * NC];
    a0 = fmaf(a[k],            w, a0);
    a1 = fmaf(a[k + KDIM],     w, a1);
    a2 = fmaf(a[k + 2 * KDIM], w, a2);
    a3 = fmaf(a[k + 3 * KDIM], w, a3);
  }
  float bb = bias[c];
  out[(size_t)(r0 + 0) * NC + c] = a0 + bb;
  out[(size_t)(r0 + 1) * NC + c] = a1 + bb;
  out[(size_t)(r0 + 2) * NC + c] = a2 + bb;
  out[(size_t)(r0 + 3) * NC + c] = a3 + bb;
}

// ---------------- Multi-commit greedy NMS decode (K=16) ----------------
// Round: all write candidate -> barrier A -> wave0 extracts exact top-16 (DPP),
// validates chain (3 ballots), publishes packed (row<<8|cls) winners + p via
// LDS -> barrier B -> all threads apply in two groups of 8 + recompute.
template <bool FAST>
__global__ __launch_bounds__(512) void decode_kernel(
    const float* __restrict__ lp, const float* __restrict__ tl,
    const float* __restrict__ boxes /* FAST: bt [NC][NB][4]; else raw */,
    float* __restrict__ commits)
{
  __shared__ ull cand[NB];    // 4 KB
  __shared__ int swin[NK];
  __shared__ int s_p;
  const int j = threadIdx.x;
  const int lane = j & 63;

  float lv[8]; int lc[8];
  float m_ = 0.f, s_ = 1.f;
  const float* xr = FAST ? (lp + (size_t)j * PST) : (lp + (size_t)j * NC);

  if (FAST) {
    const float4* tl4 = (const float4*)(tl + (size_t)j * 16);
    float4 a0 = tl4[0], a1 = tl4[1], b0 = tl4[2], b1 = tl4[3];
    lv[0] = a0.x; lv[1] = a0.y; lv[2] = a0.z; lv[3] = a0.w;
    lv[4] = a1.x; lv[5] = a1.y; lv[6] = a1.z; lv[7] = a1.w;
    lc[0] = __float_as_int(b0.x); lc[1] = __float_as_int(b0.y);
    lc[2] = __float_as_int(b0.z); lc[3] = __float_as_int(b0.w);
    lc[4] = __float_as_int(b1.x); lc[5] = __float_as_int(b1.y);
    lc[6] = __float_as_int(b1.z); lc[7] = __float_as_int(b1.w);
  } else {
#pragma unroll
    for (int t = 0; t < 8; ++t) { lv[t] = -3.4e38f; lc[t] = 0; }
    m_ = xr[0];
    for (int c = 1; c < NC; ++c) m_ = fmaxf(m_, xr[c]);
    s_ = 0.f;
    for (int c = 0; c < NC; ++c) s_ += expf(xr[c] - m_);
    for (int c = 1; c < NC; ++c) {
      float v = expf(xr[c] - m_) / s_;
      if (v > lv[7]) {
        lv[7] = v; lc[7] = c;
#pragma unroll
        for (int q = 7; q > 0; --q) {
          if (lv[q] > lv[q - 1]) {
            float tv = lv[q]; lv[q] = lv[q - 1]; lv[q - 1] = tv;
            int tc = lc[q]; lc[q] = lc[q - 1]; lc[q - 1] = tc;
          }
        }
      }
    }
  }

  float rowmax; int argcls; bool zstuck = false;
  if (lv[0] > 0.f) { rowmax = lv[0]; argcls = lc[0]; }
  else { rowmax = 0.f; argcls = 0; zstuck = true; }

  unsigned mask[5] = {0, 0, 0, 0, 0};
  bool retired = false;
  int post_min = INT_MAX;
  int commitcls = 0;
  int committed = 0;

  while (committed < NB) {
    cand[j] = ((ull)(unsigned)__float_as_int(rowmax) << 32) | (unsigned)(j * NC + argcls);
    __syncthreads();   // A

    if (j < 64) {
      // ---- wave 0: gather + exact top-16 extraction ----
      float vv[8]; int vi[8];
#pragma unroll
      for (int t = 0; t < 8; ++t) {
        ull k = cand[lane + 64 * t];
        vv[t] = __int_as_float((int)(k >> 32));
        vi[t] = (int)(unsigned)(k & 0xFFFFFFFFu);
      }
      float lmv = vv[0]; int lmi = vi[0];
#pragma unroll
      for (int t = 1; t < 8; ++t) if (vv[t] > lmv) { lmv = vv[t]; lmi = vi[t]; }

      int pk[NK]; unsigned okm = 0;
      int kmax = NB - committed; if (kmax > NK) kmax = NK;
      bool stop = false;
#pragma unroll
      for (int t = 0; t < NK; ++t) {
        if (t >= kmax || stop) { pk[t] = -1; continue; }
        float gv = wave_max_bcast(lmv);
        ull tied = __ballot(lmv == gv);
        int gi;
        if (__popcll(tied) == 1) {
          gi = __builtin_amdgcn_readlane(lmi, (int)__ffsll(tied) - 1);
        } else {
          gi = wave_min_bcast_i((lmv == gv) ? lmi : INT_MAX);  // exact min-flat-idx tie-break
        }
        int row = gi / NC;
        pk[t] = (row << 8) | (gi - row * NC);
        if (gv > 0.f) okm |= (1u << t); else stop = true;
        if (lmi == gi) {   // winner lane pops and rescans its 8
#pragma unroll
          for (int u = 0; u < 8; ++u) if (vi[u] == gi) vv[u] = -3.0e38f;
          lmv = vv[0]; lmi = vi[0];
#pragma unroll
          for (int u = 1; u < 8; ++u) if (vv[u] > lmv) { lmv = vv[u]; lmi = vi[u]; }
        }
      }

      // publish winners (packed) to LDS
      {
        int mypk = pk[0];
#pragma unroll
        for (int t = 1; t < NK; ++t) mypk = (lane == t) ? pk[t] : mypk;
        if (lane < NK) swin[lane] = mypk;
      }

      // ---- chain validity: 3 pair-sets, 3 ballots ----
      auto pick = [&](int idx) {
        int v = pk[0];
#pragma unroll
        for (int t = 1; t < NK; ++t) v = (idx == t) ? pk[t] : v;
        return v;
      };
      auto supf = [&](int pT, int pS) -> bool {
        if (pT < 0 || pS < 0) return false;
        int cT = pT & 255, cS = pS & 255;
        if (cT != cS) return false;
        float4 bs, btx;
        if (FAST) {
          bs  = *(const float4*)(boxes + ((size_t)cS * NB + (pS >> 8)) * 4);
          btx = *(const float4*)(boxes + ((size_t)cT * NB + (pT >> 8)) * 4);
        } else {
          bs  = *(const float4*)(boxes + ((size_t)(pS >> 8) * NC + cS) * 4);
          btx = *(const float4*)(boxes + ((size_t)(pT >> 8) * NC + cT) * 4);
        }
        return overlap_ge(bs, btx);
      };
      int hi = lane >> 3, lo = lane & 7;
      int pT1 = pick(hi), pS1 = pick(lo);          // BA: pair (hi, lo), lo<hi
      int pT2 = pick(8 + hi);                      // BB: pair (8+hi, lo)
      int pS3 = pick(8 + lo);                      // BC: pair (8+hi, 8+lo), lo<hi
      bool sA2 = (lo < hi) && supf(pT1, pS1);
      bool sB2 = supf(pT2, pS1);
      bool sC2 = (lo < hi) && supf(pT2, pS3);
      ull BA = __ballot(sA2);
      ull BB = __ballot(sB2);
      ull BC = __ballot(sC2);

      unsigned validset = 1; int p = 1;
#pragma unroll
      for (int t = 1; t < 8; ++t) {
        unsigned cm = (unsigned)((BA >> (8 * t)) & 0xFF) & (validset & 0xFF);
        if (p == t && ((okm >> t) & 1u) && cm == 0u) { validset |= (1u << t); p = t + 1; }
      }
#pragma unroll
      for (int t = 8; t < NK; ++t) {
        unsigned cmlo = (unsigned)((BB >> (8 * (t - 8))) & 0xFF) & (validset & 0xFF);
        unsigned cmhi = (unsigned)((BC >> (8 * (t - 8))) & 0xFF) & ((validset >> 8) & 0xFF);
        if (p == t && ((okm >> t) & 1u) && cmlo == 0u && cmhi == 0u) {
          validset |= (1u << t); p = t + 1;
        }
      }
      if (lane == 0) s_p = p;
    }
    __syncthreads();   // B

    // ---- all threads: apply the p commits in order, two groups of 8 ----
    const int p = s_p;
#pragma unroll
    for (int g = 0; g < 2; ++g) {
      if (g * 8 < p) {
        int rows_[8], cls_[8];
        float4 cb[8], ob[8];
#pragma unroll
        for (int u = 0; u < 8; ++u) {
          int t = g * 8 + u;
          int pkv = __builtin_amdgcn_readfirstlane(swin[t]);   // uniform scalar
          rows_[u] = pkv >> 8; cls_[u] = pkv & 255;
          if (t < p) {
            if (FAST) {
              const float* btc = boxes + (size_t)cls_[u] * NB * 4;
              cb[u] = *(const float4*)(btc + (size_t)rows_[u] * 4);  // s_load (uniform)
              ob[u] = *(const float4*)(btc + (size_t)j * 4);         // lane-dense
            } else {
              cb[u] = *(const float4*)(boxes + ((size_t)rows_[u] * NC + cls_[u]) * 4);
              ob[u] = *(const float4*)(boxes + ((size_t)j * NC + cls_[u]) * 4);
            }
          }
        }
#pragma unroll
        for (int u = 0; u < 8; ++u) {
          int t = g * 8 + u;
          if (t < p) {
            if (j == rows_[u]) {
              // commit: col update overwritten by row := -1 (reference order)
              retired = true; commitcls = cls_[u]; post_min = INT_MAX;
            } else if (overlap_ge(cb[u], ob[u])) {
              if (retired) {
                post_min = (cls_[u] < post_min) ? cls_[u] : post_min;  // resurrect -1 -> 0.0
              } else {
                int c = cls_[u];
#pragma unroll
                for (int k5 = 0; k5 < 5; ++k5) if (k5 == (c >> 5)) mask[k5] |= (1u << (c & 31));
              }
            }
          }
        }
      }
    }

    // ---- recompute my candidate ----
    if (retired) {
      rowmax = (post_min != INT_MAX) ? 0.0f : -1.0f;
      argcls = (post_min != INT_MAX) ? post_min : 0;
    } else if (!zstuck) {
      bool found = false;
#pragma unroll
      for (int t = 0; t < 8; ++t) {
        if (!found && lv[t] > 0.f && !mbit(mask, lc[t])) {
          rowmax = lv[t]; argcls = lc[t]; found = true;
        }
      }
      if (!found) {
        // rare: full rescan with list refill. FAST: stored probs, no transcendentals.
        float bm = -3.4e38f; int ba = 0;
#pragma unroll
        for (int t = 0; t < 8; ++t) { lv[t] = -3.4e38f; lc[t] = 0; }
        auto ins = [&](float v, int c) {
          if (v > lv[7]) {
            lv[7] = v; lc[7] = c;
#pragma unroll
            for (int q = 7; q > 0; --q) {
              if (lv[q] > lv[q - 1]) {
                float tv = lv[q]; lv[q] = lv[q - 1]; lv[q - 1] = tv;
                int tc = lc[q]; lc[q] = lc[q - 1]; lc[q - 1] = tc;
              }
            }
          }
        };
        if (FAST) {
          for (int c4 = 0; c4 < PST / 4; ++c4) {
            float4 v4 = *(const float4*)(xr + c4 * 4);   // probs; class0=0, pad=0
            int c = c4 * 4;
            float vals[4] = {v4.x, v4.y, v4.z, v4.w};
#pragma unroll
            for (int u = 0; u < 4; ++u) {
              int cc = c + u;
              float v = mbit(mask, cc) ? 0.f : vals[u];
              if (v > bm) { bm = v; ba = cc; }   // cc=0 (v=0) hits first; pads never exceed
              if (v > 0.f) ins(v, cc);
            }
          }
        } else {
          for (int c = 0; c < NC; ++c) {
            float v;
            if (c == 0) v = 0.f;
            else v = mbit(mask, c) ? 0.f : (expf(xr[c] - m_) / s_);
            if (v > bm) { bm = v; ba = c; }
            if (v > 0.f) ins(v, c);
          }
        }
        rowmax = bm; argcls = ba;
        if (!(bm > 0.f)) zstuck = true;   // all-zero row: candidate stable forever
      }
    }
    // zstuck: keep (rowmax, argcls) — values never increase for this row

    committed += p;
  }

  commits[j] = (float)commitcls;
}

extern "C" void kernel_launch(void* const* d_in, const int* in_sizes, int n_in,
                              void* d_out, int out_size, void* d_ws, size_t ws_size,
                              hipStream_t stream) {
  const float* A     = (const float*)d_in[0];   // obj_fmap [512,4096]
  const float* boxes = (const float*)d_in[1];   // boxes_per_cls [512,151,4]
  const float* W     = (const float*)d_in[2];   // [4096,151]
  const float* bias  = (const float*)d_in[3];   // [151]
  float* out = (float*)d_out;                   // [512*151] obj_dists ++ [512] commits

  const size_t np = (size_t)KS * NB * PST;      // part
  const size_t nl = (size_t)NB * PST;           // lp
  const size_t nt = (size_t)NB * 16;            // tl
  const size_t nb = (size_t)NC * NB * 4;        // bt
  const size_t need = (np + nl + nt + nb) * 4;

  if (ws_size >= need) {
    float* part = (float*)d_ws;
    float* lp   = part + np;
    float* tl   = lp + nl;
    float* bt   = tl + nt;
    gemm_fused<<<TPB_GEMM + NTR, 192, 0, stream>>>(A, W, boxes, part, bt);
    prep_kernel<<<NB / 64, 64, 0, stream>>>(part, bias, out, lp, tl);
    decode_kernel<true><<<1, NB, 0, stream>>>(lp, tl, bt, out + NB * NC);
  } else {
    gemm_full<<<NB / 4, 192, 0, stream>>>(A, W, bias, out);
    decode_kernel<false><<<1, NB, 0, stream>>>(out, nullptr, boxes, out + NB * NC);
  }
}